// Round 17
// baseline (1299.704 us; speedup 1.0000x reference)
//
#include <hip/hip_runtime.h>
#include <stdint.h>
#include <stddef.h>

// Problem dims
#define Bn   64
#define Tn   512
#define DINn 512
#define Hn   1024
#define OUTn 128

typedef __attribute__((ext_vector_type(4))) float f32x4;
typedef __attribute__((ext_vector_type(8))) short short8;
typedef __attribute__((ext_vector_type(4))) unsigned int u32x4;

__device__ __forceinline__ unsigned short f2bf(float f){
  unsigned int x = __builtin_bit_cast(unsigned int, f);
  x += 0x7fffu + ((x >> 16) & 1u);           // RNE (values bounded, no NaN/inf)
  return (unsigned short)(x >> 16);
}
__device__ __forceinline__ float bf2f(unsigned short u){
  return __builtin_bit_cast(float, (unsigned int)u << 16);
}
__device__ __forceinline__ float tanh_fast(float v){
  float e = __expf(2.0f * v);
  return 1.0f - 2.0f / (e + 1.0f);
}

// lgkm-only barrier (no vmcnt drain): poison protocol needs no store drain.
#define LGKM_BAR() asm volatile("s_waitcnt lgkmcnt(0)\ns_barrier" ::: "memory")

// ---- protocol primitives ----
// MODE 0 + POISON: data-is-the-flag. Producers sc0-store slices into write-once poisoned
//   regions; consumers nt-poll their own chunks until != 0xFFFF (bf16 NaN; unreachable
//   by finite tanh/linear outputs). h2 tiles alias pre0 blocks; each role0 LANE poisons
//   exactly the pre0 cells IT prefetched, after its own vmcnt drain (r16 lesson: poisoning
//   other lanes' cells races their in-flight prefetch loads).
// MODE 0 (flag, r14-proven): per-wave NT flag lines. MODE 1 (ATOM, r9). MODE 2 (MALL, r4).
template<bool FAST>
__device__ __forceinline__ void st16(unsigned short* p, u32x4 v){
  if constexpr (FAST)
    asm volatile("global_store_dwordx4 %0, %1, off sc0" :: "v"(p), "v"(v) : "memory");
  else
    asm volatile("global_store_dwordx4 %0, %1, off sc0 sc1" :: "v"(p), "v"(v) : "memory");
}
__device__ __forceinline__ unsigned atom_poll(unsigned int* p){
  unsigned old, zero = 0;
  asm volatile("global_atomic_add %0, %1, %2, off sc0\n\t"
               "s_waitcnt vmcnt(0)"
               : "=&v"(old) : "v"(p), "v"(zero) : "memory");
  return old;
}
__device__ __forceinline__ void atom_poll2(unsigned int* p1, unsigned int* p2,
                                           unsigned &v1, unsigned &v2){
  unsigned zero = 0;
  asm volatile("global_atomic_add %0, %2, %4, off sc0\n\t"
               "global_atomic_add %1, %3, %4, off sc0\n\t"
               "s_waitcnt vmcnt(0)"
               : "=&v"(v1), "=&v"(v2)
               : "v"(p1), "v"(p2), "v"(zero) : "memory");
}
__device__ __forceinline__ void atom_inc(unsigned int* p){
  unsigned one = 1;
  asm volatile("global_atomic_add %0, %1, off" :: "v"(p), "v"(one) : "memory");
}
__device__ __forceinline__ unsigned ld1_sc0(const unsigned int* p){
  unsigned v;
  asm volatile("global_load_dword %0, %1, off sc0\n\t"
               "s_waitcnt vmcnt(0)" : "=&v"(v) : "v"(p) : "memory");
  return v;
}
__device__ __forceinline__ unsigned ld1_nt(const unsigned int* p){
  unsigned v;
  asm volatile("global_load_dword %0, %1, off nt\n\t"
               "s_waitcnt vmcnt(0)" : "=&v"(v) : "v"(p) : "memory");
  return v;
}
__device__ __forceinline__ void ld2_nt(const unsigned int* p1, const unsigned int* p2,
                                       unsigned &v1, unsigned &v2){
  asm volatile("global_load_dword %0, %2, off nt\n\t"
               "global_load_dword %1, %3, off nt\n\t"
               "s_waitcnt vmcnt(0)"
               : "=&v"(v1), "=&v"(v2) : "v"(p1), "v"(p2) : "memory");
}
__device__ __forceinline__ unsigned umin4(u32x4 a){
  unsigned m0 = a[0] < a[1] ? a[0] : a[1];
  unsigned m1 = a[2] < a[3] ? a[2] : a[3];
  return m0 < m1 ? m0 : m1;
}
__device__ __forceinline__ unsigned ld_line8_slow(const unsigned int* p){
  u32x4 a, b;
  asm volatile("global_load_dwordx4 %0, %2, off sc0 sc1\n\t"
               "global_load_dwordx4 %1, %3, off sc0 sc1\n\t"
               "s_waitcnt vmcnt(0)"
               : "=&v"(a), "=&v"(b) : "v"(p), "v"(p + 4) : "memory");
  unsigned ma = umin4(a), mb = umin4(b);
  return ma < mb ? ma : mb;
}
// Bounded waits. Worst case returns late -> visibly wrong, never a hang.
__device__ __forceinline__ void waitw_nt(const unsigned int* p, unsigned want){
  if (!want) return;
  for (int i = 0; i < (1 << 16); ++i){
    if (ld1_nt(p) >= want) return;
    if (i > 16) __builtin_amdgcn_s_sleep(1);
  }
}
__device__ __forceinline__ void waitw_nt2(const unsigned int* p1, unsigned w1,
                                          const unsigned int* p2, unsigned w2){
  if (!w1){ waitw_nt(p2, w2); return; }
  for (int i = 0; i < (1 << 16); ++i){
    unsigned v1, v2;
    ld2_nt(p1, p2, v1, v2);
    if (v1 >= w1 && v2 >= w2) return;
    if (i > 16) __builtin_amdgcn_s_sleep(1);
  }
}
template<bool FAST>
__device__ __forceinline__ void wait_one(unsigned int* fc, unsigned int* fl, unsigned wfast, unsigned wslow){
  if constexpr (FAST){
    if (!wfast) return;
    for (int i = 0; i < (1 << 16); ++i){
      if (atom_poll(fc) >= wfast) return;
      if (i > 8) __builtin_amdgcn_s_sleep(1);
    }
  } else {
    if (!wslow) return;
    for (int i = 0; i < (1 << 16); ++i){
      if (ld_line8_slow(fl) >= wslow) return;
      if (i > 16) __builtin_amdgcn_s_sleep(1);
    }
  }
}
template<bool FAST>
__device__ __forceinline__ void wait_dual(unsigned int* fc1, unsigned int* fl1, unsigned wf1, unsigned ws1,
                                          unsigned int* fc2, unsigned int* fl2, unsigned wf2, unsigned ws2){
  if constexpr (FAST){
    if (!wf2){ wait_one<true>(fc1, fl1, wf1, ws1); return; }
    for (int i = 0; i < (1 << 16); ++i){
      unsigned v1, v2;
      atom_poll2(fc1, fc2, v1, v2);
      if (v1 >= wf1 && v2 >= wf2) return;
      if (i > 8) __builtin_amdgcn_s_sleep(1);
    }
  } else {
    if (!ws2){ wait_one<false>(fc1, fl1, wf1, ws1); return; }
    for (int i = 0; i < (1 << 16); ++i){
      if (ld_line8_slow(fl1) >= ws1 && ld_line8_slow(fl2) >= ws2) return;
      if (i > 16) __builtin_amdgcn_s_sleep(1);
    }
  }
}

// ---- poison-poll primitives ----
__device__ __forceinline__ bool chk8(u32x4 v){
  bool ok = true;
#pragma unroll
  for (int d = 0; d < 4; ++d){
    ok = ok && ((v[d] & 0xFFFFu) != 0xFFFFu) && ((v[d] >> 16) != 0xFFFFu);
  }
  return ok;
}
// Per-lane: poll own 2 chunks (16B each) until non-poison, then write to LDS slice.
__device__ __forceinline__ void poison_stage(const unsigned short* src, unsigned short* dst, int lane){
  const unsigned short* p0 = src + lane*8;
  const unsigned short* p1 = p0 + 512;
  u32x4 v0, v1;
  bool ok = false;
  for (int i = 0; i < (1 << 16) && !ok; ++i){
    asm volatile("global_load_dwordx4 %0, %2, off nt\n\t"
                 "global_load_dwordx4 %1, %3, off nt\n\t"
                 "s_waitcnt vmcnt(0)"
                 : "=&v"(v0), "=&v"(v1) : "v"(p0), "v"(p1) : "memory");
    ok = chk8(v0) && chk8(v1);
    if (!ok && i > 4) __builtin_amdgcn_s_sleep(1);
  }
  *(u32x4*)(dst + lane*8) = v0;
  *(u32x4*)(dst + lane*8 + 512) = v1;
}
// Poll 4 bf16 (stride 8 shorts) until non-poison (active lanes only).
__device__ __forceinline__ void poison_pv(const unsigned short* p, float* pv, bool active){
  unsigned u0 = 0, u1 = 0, u2 = 0, u3 = 0;
  bool ok = !active;
  for (int i = 0; i < (1 << 16) && !ok; ++i){
    asm volatile("global_load_ushort %0, %4, off nt\n\t"
                 "global_load_ushort %1, %5, off nt\n\t"
                 "global_load_ushort %2, %6, off nt\n\t"
                 "global_load_ushort %3, %7, off nt\n\t"
                 "s_waitcnt vmcnt(0)"
                 : "=&v"(u0), "=&v"(u1), "=&v"(u2), "=&v"(u3)
                 : "v"(p), "v"(p + 8), "v"(p + 16), "v"(p + 24) : "memory");
    ok = (u0 != 0xFFFFu) && (u1 != 0xFFFFu) && (u2 != 0xFFFFu) && (u3 != 0xFFFFu);
    if (!ok && i > 4) __builtin_amdgcn_s_sleep(1);
  }
  pv[0] = bf2f((unsigned short)u0); pv[1] = bf2f((unsigned short)u1);
  pv[2] = bf2f((unsigned short)u2); pv[3] = bf2f((unsigned short)u3);
}

// Per-wave 2KB slice copy global->LDS (flag mode).
__device__ __forceinline__ void stage_pw(const unsigned short* src, unsigned short* dst, int lane){
  const unsigned short* p0 = src + lane*8;
  const unsigned short* p1 = p0 + 512;
  u32x4 v0, v1;
  asm volatile("global_load_dwordx4 %0, %2, off sc0\n\t"
               "global_load_dwordx4 %1, %3, off sc0\n\t"
               "s_waitcnt vmcnt(0)"
               : "=&v"(v0), "=&v"(v1) : "v"(p0), "v"(p1) : "memory");
  *(u32x4*)(dst + lane*8) = v0;
  *(u32x4*)(dst + lane*8 + 512) = v1;
}
// Per-wave 2KB slice + 4 bf16 pv loads, one drain (flag mode).
__device__ __forceinline__ void stage_pw_pv(const unsigned short* src, unsigned short* dst, int lane,
                                            const unsigned short* p4, float* pv){
  const unsigned short* p0 = src + lane*8;
  const unsigned short* p1 = p0 + 512;
  u32x4 v0, v1; unsigned u0,u1,u2,u3;
  asm volatile(
    "global_load_dwordx4 %0, %6, off sc0\n\t"
    "global_load_dwordx4 %1, %7, off sc0\n\t"
    "global_load_ushort %2, %8, off sc0\n\t"
    "global_load_ushort %3, %9, off sc0\n\t"
    "global_load_ushort %4, %10, off sc0\n\t"
    "global_load_ushort %5, %11, off sc0\n\t"
    "s_waitcnt vmcnt(0)"
    : "=&v"(v0),"=&v"(v1),"=&v"(u0),"=&v"(u1),"=&v"(u2),"=&v"(u3)
    : "v"(p0),"v"(p1),"v"(p4),"v"(p4+8),"v"(p4+16),"v"(p4+24) : "memory");
  *(u32x4*)(dst + lane*8) = v0;
  *(u32x4*)(dst + lane*8 + 512) = v1;
  pv[0]=bf2f((unsigned short)u0); pv[1]=bf2f((unsigned short)u1);
  pv[2]=bf2f((unsigned short)u2); pv[3]=bf2f((unsigned short)u3);
}

// Linear 16KB tile copy global->LDS (fallback modes).
template<bool FAST>
__device__ __forceinline__ void stage_lin(const unsigned short* base, unsigned short* hl, int tid){
  const unsigned short* p0 = base + (size_t)tid * 8;
  const unsigned short* p1 = p0 + 4096;
  u32x4 v0, v1;
  if constexpr (FAST)
    asm volatile("global_load_dwordx4 %0, %2, off sc0\n\t"
                 "global_load_dwordx4 %1, %3, off sc0\n\t"
                 "s_waitcnt vmcnt(0)"
                 : "=&v"(v0), "=&v"(v1) : "v"(p0), "v"(p1) : "memory");
  else
    asm volatile("global_load_dwordx4 %0, %2, off sc0 sc1\n\t"
                 "global_load_dwordx4 %1, %3, off sc0 sc1\n\t"
                 "s_waitcnt vmcnt(0)"
                 : "=&v"(v0), "=&v"(v1) : "v"(p0), "v"(p1) : "memory");
  *(u32x4*)((char*)hl + tid * 16) = v0;
  *(u32x4*)((char*)hl + tid * 16 + 8192) = v1;
}
// 4 bf16 scalar loads, chunk-order row walk (stride 8 shorts)
template<bool FAST>
__device__ __forceinline__ void ld4_chunk(const unsigned short* p, float* pv){
  unsigned u0,u1,u2,u3;
  if constexpr (FAST)
    asm volatile("global_load_ushort %0, %4, off sc0\n\t"
                 "global_load_ushort %1, %5, off sc0\n\t"
                 "global_load_ushort %2, %6, off sc0\n\t"
                 "global_load_ushort %3, %7, off sc0\n\t"
                 "s_waitcnt vmcnt(0)"
                 : "=&v"(u0), "=&v"(u1), "=&v"(u2), "=&v"(u3)
                 : "v"(p), "v"(p + 8), "v"(p + 16), "v"(p + 24) : "memory");
  else
    asm volatile("global_load_ushort %0, %4, off sc0 sc1\n\t"
                 "global_load_ushort %1, %5, off sc0 sc1\n\t"
                 "global_load_ushort %2, %6, off sc0 sc1\n\t"
                 "global_load_ushort %3, %7, off sc0 sc1\n\t"
                 "s_waitcnt vmcnt(0)"
                 : "=&v"(u0), "=&v"(u1), "=&v"(u2), "=&v"(u3)
                 : "v"(p), "v"(p + 8), "v"(p + 16), "v"(p + 24) : "memory");
  pv[0] = bf2f((unsigned short)u0); pv[1] = bf2f((unsigned short)u1);
  pv[2] = bf2f((unsigned short)u2); pv[3] = bf2f((unsigned short)u3);
}

// MFMA sweep over K=1024 on chunk-ordered LDS tile (conflict-free, r12-proven).
__device__ __forceinline__ f32x4 mfma_tile(const char* lbase, const short8* wf, int lrow, int kh){
  f32x4 a0 = {0.f,0.f,0.f,0.f}, a1 = a0, a2 = a0, a3 = a0;
  int rb = kh * 128 + lrow * 16;
#pragma unroll
  for (int kk = 0; kk < 8; ++kk)
    a0 = __builtin_amdgcn_mfma_f32_16x16x32_bf16(*(const short8*)(lbase + kk*512 + rb), wf[kk], a0, 0,0,0);
#pragma unroll
  for (int kk = 8; kk < 16; ++kk)
    a1 = __builtin_amdgcn_mfma_f32_16x16x32_bf16(*(const short8*)(lbase + kk*512 + rb), wf[kk], a1, 0,0,0);
#pragma unroll
  for (int kk = 16; kk < 24; ++kk)
    a2 = __builtin_amdgcn_mfma_f32_16x16x32_bf16(*(const short8*)(lbase + kk*512 + rb), wf[kk], a2, 0,0,0);
#pragma unroll
  for (int kk = 24; kk < 32; ++kk)
    a3 = __builtin_amdgcn_mfma_f32_16x16x32_bf16(*(const short8*)(lbase + kk*512 + rb), wf[kk], a3, 0,0,0);
  return (a0 + a1) + (a2 + a3);
}

// ---------------- elementwise f32 -> bf16 ----------------
__global__ void cvt_bf16x8(const float* __restrict__ in, unsigned short* __restrict__ out,
                           long long n8){
  long long i = (long long)blockIdx.x * blockDim.x + threadIdx.x;
  long long stride = (long long)gridDim.x * blockDim.x;
  for (; i < n8; i += stride){
    const float* p = in + i*8;
    float4 a = *(const float4*)p;
    float4 b = *(const float4*)(p+4);
    short8 v;
    v[0]=(short)f2bf(a.x); v[1]=(short)f2bf(a.y); v[2]=(short)f2bf(a.z); v[3]=(short)f2bf(a.w);
    v[4]=(short)f2bf(b.x); v[5]=(short)f2bf(b.y); v[6]=(short)f2bf(b.z); v[7]=(short)f2bf(b.w);
    *(short8*)(out + i*8) = v;
  }
}

__global__ void bias_combine(const float* __restrict__ a, const float* __restrict__ b, float* __restrict__ o,
                             const float* __restrict__ c, const float* __restrict__ d, float* __restrict__ p){
  int i = blockIdx.x * blockDim.x + threadIdx.x;
  if (i < Hn){ o[i] = a[i] + b[i]; p[i] = c[i] + d[i]; }
}

// ---------------- pre0 GEMM: C[t*Bn+b][n] = sum_k x[b*Tn+t][k]*Wih0[n][k] + bias[n] ----------
__launch_bounds__(256, 2)
__global__ void gemm_pre0(const float* __restrict__ Av, const unsigned short* __restrict__ Bm,
                          const float* __restrict__ bias, unsigned short* __restrict__ C,
                          int N, int K)
{
  __shared__ unsigned short lA[128*64];
  __shared__ unsigned short lB[128*64];
  int bn = blockIdx.x, bm = blockIdx.y;
  int m0 = bm*128, n0 = bn*128;
  int tid = threadIdx.x, lane = tid & 63, w = tid >> 6;
  int wm = (w >> 1)*64, wn = (w & 1)*64;
  int cl = lane & 15, kh = lane >> 4;

  f32x4 acc[4][4];
  f32x4 z = {0.f,0.f,0.f,0.f};
#pragma unroll
  for (int i=0;i<4;i++)
#pragma unroll
    for (int j=0;j<4;j++) acc[i][j]=z;

  for (int k0 = 0; k0 < K; k0 += 64){
    __syncthreads();
#pragma unroll
    for (int r = 0; r < 4; ++r){
      int c = r*256 + tid;
      int row = c >> 3, cof = (c & 7)*8;
      const float* ap = Av + (size_t)(m0+row)*K + k0 + cof;
      float4 a = *(const float4*)ap;
      float4 b = *(const float4*)(ap+4);
      short8 v;
      v[0]=(short)f2bf(a.x); v[1]=(short)f2bf(a.y); v[2]=(short)f2bf(a.z); v[3]=(short)f2bf(a.w);
      v[4]=(short)f2bf(b.x); v[5]=(short)f2bf(b.y); v[6]=(short)f2bf(b.z); v[7]=(short)f2bf(b.w);
      *(short8*)&lA[row*64 + cof] = v;
      const unsigned short* bp = Bm + (size_t)(n0+row)*K + k0 + cof;
      *(short8*)&lB[row*64 + cof] = *(const short8*)bp;
    }
    __syncthreads();
#pragma unroll
    for (int kk = 0; kk < 2; ++kk){
      int kb = kk*32 + kh*8;
      short8 af[4], bfr[4];
#pragma unroll
      for (int i=0;i<4;i++) af[i]  = *(const short8*)&lA[(wm + i*16 + cl)*64 + kb];
#pragma unroll
      for (int j=0;j<4;j++) bfr[j] = *(const short8*)&lB[(wn + j*16 + cl)*64 + kb];
#pragma unroll
      for (int i=0;i<4;i++)
#pragma unroll
        for (int j=0;j<4;j++)
          acc[i][j] = __builtin_amdgcn_mfma_f32_16x16x32_bf16(af[i], bfr[j], acc[i][j], 0,0,0);
    }
  }
#pragma unroll
  for (int j=0;j<4;j++){
    int n = n0 + wn + j*16 + cl;
    float bs = bias[n];
#pragma unroll
    for (int i=0;i<4;i++){
      int mr = m0 + wm + i*16 + kh*4;
#pragma unroll
      for (int e=0;e<4;e++){
        int m = mr + e;                       // m = b*Tn + t
        int b = m >> 9, t = m & (Tn-1);
        C[((size_t)t*Bn + b)*N + n] = f2bf(acc[i][j][e] + bs);
      }
    }
  }
}

// ---------------- fused 3-stage recurrence ----------------
// 192 wgs, g = bx&7 (one XCD, runtime-verified); sub = bx>>3: role = sub>>3
// (0:L0-rec, 1:pre1-GEMV, 2:L1-rec), slot = sub&7 -> cols [128*slot,+128).
// Chunk-ordered 16KB tiles; slice s = contiguous 2KB at tile+s*1024 shorts.
// Tile idx i at base+(i*8+g)*8192. h1(t)->h1base tile t+2; pre1(t)->pre1base tile t;
// h2(t)->h2base tile t. POISON: h2base==pre0 (aliased); each role0 lane poisons its own
// consumed pre0 cells post-drain; poison drained before h1 publish -> precedes h2 write.
template<int MODE, bool POISON>
__device__ __forceinline__ void rnn_body(
    int role, int g, int slot, int tid, int w, int lane, int cl, int kh, int lrow,
    const unsigned short* pre0, unsigned short* h1base, unsigned short* pre1base,
    unsigned short* h2base, const float* bias1,
    unsigned int* FCA0, unsigned int* FCA1, unsigned int* FCB, unsigned int* FCC,
    unsigned int* FLA, unsigned int* FLB, unsigned int* FLC,
    unsigned int* FNA, unsigned int* FNB, unsigned int* FNC,
    const short8* wf, unsigned short* hl, unsigned short* outl)
{
  constexpr bool FAST = (MODE < 2);
  int n0 = slot*128 + w*16;
  int olocal = w*128 + ((cl>>3)*8 + kh*4)*8 + (cl&7);    // j stride 8 shorts
  int khc = kh & 1;
  unsigned int* myFL = ((role == 0) ? FLA : (role == 1) ? FLB : FLC) + slot;
  unsigned int* myFN = ((role == 0) ? FNA : (role == 1) ? FNB : FNC) + slot;

  for (int t = 0; t < Tn; ++t){
    int obuf = (MODE == 0 && POISON) ? (t & 1) : 0;
    unsigned short* hlb = hl + obuf*8192;
    unsigned short* olb = outl + obuf*1024;
    const char* lbase = (const char*)hlb;

    float pv[4] = {0.f,0.f,0.f,0.f};
    const unsigned short* pp = nullptr;
    if (role == 0 && kh < 2){            // prefetch pre0 (plain cached; slice immutable here)
      pp = pre0 + ((size_t)t*Bn + g*8 + kh*4)*Hn + n0 + cl;
#pragma unroll
      for (int j=0;j<4;j++) pv[j] = bf2f(pp[(size_t)j*Hn]);
    }
    bool staged = true;
    if constexpr (MODE == 0 && POISON){
      // ---- data-is-the-flag: per-lane poison polls; single barrier; no drains/flags ----
      if (role == 0){
        asm volatile("s_waitcnt vmcnt(0)" ::: "memory");  // own prefetch loads complete
        // per-lane self-poison: each lane poisons exactly the 4 cells IT just loaded
        if (kh < 2){
          unsigned short* pz = (unsigned short*)pp;
          unsigned pzv = 0xFFFFu;
#pragma unroll
          for (int j=0;j<4;j++)
            asm volatile("global_store_short %0, %1, off sc0" :: "v"(pz + (size_t)j*Hn), "v"(pzv) : "memory");
        }
        if (t > 0){
          poison_stage(h1base + ((size_t)(t+1)*8 + g)*8192 + w*1024, hlb + w*1024, lane); // drains poison too
        } else {
          staged = false;
          asm volatile("s_waitcnt vmcnt(0)" ::: "memory"); // drain poison before h1(0) publish
        }
      } else if (role == 1){
        poison_stage(h1base + ((size_t)(t+2)*8 + g)*8192 + w*1024, hlb + w*1024, lane);
      } else {
        const unsigned short* pA = pre1base + ((size_t)t*8 + g)*8192 + slot*1024
                                   + ((w*16+cl)>>3)*64 + khc*32 + (cl&7);
        if (t > 0) poison_stage(h2base + ((size_t)(t-1)*8 + g)*8192 + w*1024, hlb + w*1024, lane);
        else staged = false;
        poison_pv(pA, pv, kh < 2);
      }
    } else if constexpr (MODE == 0){
      // ---- per-wave NT flag detect + slice stage (r14-proven) ----
      if (role == 0){
        if (t > 0){
          waitw_nt(FNA + w, (unsigned)t);
          stage_pw(h1base + ((size_t)(t+1)*8 + g)*8192 + w*1024, hlb + w*1024, lane);
        } else staged = false;
      } else if (role == 1){
        waitw_nt(FNA + w, (unsigned)(t+1));
        stage_pw(h1base + ((size_t)(t+2)*8 + g)*8192 + w*1024, hlb + w*1024, lane);
      } else {
        const unsigned short* pA = pre1base + ((size_t)t*8 + g)*8192 + slot*1024
                                   + ((w*16+cl)>>3)*64 + khc*32 + (cl&7);
        if (t > 0){
          waitw_nt2(FNC + w, (unsigned)t, FNB + slot, (unsigned)(t+1));
          stage_pw_pv(h2base + ((size_t)(t-1)*8 + g)*8192 + w*1024, hlb + w*1024, lane, pA, pv);
        } else {
          staged = false;
          waitw_nt(FNB + slot, 1u);
          ld4_chunk<true>(pA, pv);
        }
      }
    } else {
      // ---- fallback: centralized tid0 wait + B1 + full stage (r12/r9/r4-proven) ----
      if (tid == 0){
        if (role == 0)      wait_one <FAST>(FCA0, FLA, 8u*(unsigned)t, (unsigned)t);
        else if (role == 1) wait_one <FAST>(FCA1, FLA, 8u*(unsigned)(t+1), (unsigned)(t+1));
        else                wait_dual<FAST>(FCB, FLB, 8u*(unsigned)(t+1), (unsigned)(t+1),
                                            FCC, FLC, 8u*(unsigned)t, (unsigned)t);
      }
      __syncthreads();                                             // B1
      if (role == 0){
        if (t > 0) stage_lin<FAST>(h1base + ((size_t)(t+1)*8 + g)*8192, hlb, tid);
        else staged = false;
      } else if (role == 1){
        stage_lin<FAST>(h1base + ((size_t)(t+2)*8 + g)*8192, hlb, tid);
      } else {
        if (kh < 2)
          ld4_chunk<FAST>(pre1base + ((size_t)t*8 + g)*8192 + slot*1024 + ((w*16+cl)>>3)*64 + kh*32 + (cl&7), pv);
        if (t > 0) stage_lin<FAST>(h2base + ((size_t)(t-1)*8 + g)*8192, hlb, tid);
        else staged = false;
      }
    }
    // B2: tile staged (LDS writes visible to all waves)
    if constexpr (MODE == 0 && POISON) LGKM_BAR();
    else __syncthreads();
    // ---- compute ----
    f32x4 acc = {0.f,0.f,0.f,0.f};
    if (staged) acc = mfma_tile(lbase, wf, lrow, kh);
    // ---- transpose to wave-local LDS, vector-store tile slice ----
    if (kh < 2){
      float bs = (role == 1) ? bias1[n0 + cl] : 0.f;
#pragma unroll
      for (int j=0;j<4;j++){
        float v = acc[j] + pv[j] + bs;
        if (role != 1) v = tanh_fast(v);
        olb[olocal + j*8] = f2bf(v);
      }
    }
    unsigned short* tile;
    if (role == 0)      tile = h1base + ((size_t)(t+2)*8 + g)*8192;
    else if (role == 1) tile = pre1base + ((size_t)t*8 + g)*8192;
    else                tile = h2base + ((size_t)t*8 + g)*8192;
    if (lane < 16){
      u32x4 v = *(const u32x4*)(olb + w*128 + lane*8);
      st16<FAST>(tile + slot*1024 + (w*16 + lane)*8, v);
    }
    if constexpr (MODE == 0 && POISON){
      // no second barrier: hl/outl double-buffered; consumers poll data directly
    } else {
      asm volatile("s_waitcnt vmcnt(0)" ::: "memory");
      __syncthreads();                                             // B3
      if constexpr (MODE == 0){
        if (lane == 0 && w == 0)
          asm volatile("global_store_dword %0, %1, off sc0" :: "v"(myFN), "v"((unsigned)(t+1)) : "memory");
      } else if constexpr (MODE == 1){
        if (tid == 0){
          if (role == 0){ atom_inc(FCA0); atom_inc(FCA1); }
          else if (role == 1) atom_inc(FCB);
          else atom_inc(FCC);
        }
      } else {
        if (tid == 0)
          asm volatile("global_store_dword %0, %1, off sc0 sc1" :: "v"(myFL), "v"((unsigned)(t+1)) : "memory");
      }
    }
  }
}

__launch_bounds__(512, 2)
__global__ void rnn_fused(const unsigned short* __restrict__ pre0_ro,
                          unsigned short* __restrict__ h1base,
                          unsigned short* __restrict__ pre1base,
                          unsigned short* __restrict__ h2base,
                          const float* __restrict__ Whh0,
                          const float* __restrict__ Wih1,
                          const float* __restrict__ Whh1,
                          const float* __restrict__ bias1,
                          unsigned int* ctrs, int allowPoison)
{
  __shared__ __align__(16) unsigned short hl[16384];   // 2 x 16KB staged tile (chunk order)
  __shared__ __align__(16) unsigned short outl[2048];  // 2 x 2KB, wave-local transpose
  __shared__ int s_mode;
  int bx = blockIdx.x;
  int g = bx & 7;
  int sub = bx >> 3;
  int role = sub >> 3, slot = sub & 7;
  int tid = threadIdx.x, lane = tid & 63, w = tid >> 6;
  int n0 = slot*128 + w*16;
  int cl = lane & 15, kh = lane >> 4, lrow = cl & 7;
  unsigned int* FLA = ctrs + (0*8 + g)*32;
  unsigned int* FLB = ctrs + (1*8 + g)*32;
  unsigned int* FLC = ctrs + (2*8 + g)*32;
  unsigned int* arrive1 = ctrs + 768;
  unsigned int* badAT   = ctrs + 772;
  unsigned int* arrive2 = ctrs + 776;
  unsigned int* badNT   = ctrs + 780;
  unsigned int* arrive3 = ctrs + 784;
  unsigned int* FCA0 = ctrs + 1536 + (0*8 + g)*32;
  unsigned int* FCB  = ctrs + 1536 + (1*8 + g)*32;
  unsigned int* FCC  = ctrs + 1536 + (2*8 + g)*32;
  unsigned int* FCA1 = ctrs + 1536 + (3*8 + g)*32;
  unsigned int* FNA = ctrs + 2560 + (0*8 + g)*32;
  unsigned int* FNB = ctrs + 2560 + (1*8 + g)*32;
  unsigned int* FNC = ctrs + 2560 + (2*8 + g)*32;

  // ---- one-time self-tests: NT sequence, then ATOM sequence; consensus via bad flags ----
  if (tid == 0){
    int xcc;
    asm volatile("s_getreg_b32 %0, hwreg(HW_REG_XCC_ID)" : "=s"(xcc));
    unsigned int* atw = ctrs + 1024 + g*32;  unsigned int* atarmed = atw + 16;
    unsigned int* ntw = ctrs + 3328 + g*32;  unsigned int* ntarmed = ntw + 16;
    if (xcc != g){
      __hip_atomic_fetch_or(badNT, 1u, __ATOMIC_RELAXED, __HIP_MEMORY_SCOPE_AGENT);
      __hip_atomic_fetch_or(badAT, 1u, __ATOMIC_RELAXED, __HIP_MEMORY_SCOPE_AGENT);
    }
    unsigned pr = ld1_nt(ntw) + ld1_nt(ntarmed);   // prime NT lines (stale-L1 hazard probe)
    asm volatile("" :: "v"(pr));
    __hip_atomic_fetch_add(arrive1, 1u, __ATOMIC_ACQ_REL, __HIP_MEMORY_SCOPE_AGENT);
    int t1 = 0;
    for (int i = 0; i < (1 << 20); ++i){
      if (__hip_atomic_load(arrive1, __ATOMIC_ACQUIRE, __HIP_MEMORY_SCOPE_AGENT) >= 192u){ t1 = 1; break; }
      __builtin_amdgcn_s_sleep(2);
    }
    if (!t1){
      __hip_atomic_fetch_or(badNT, 1u, __ATOMIC_RELAXED, __HIP_MEMORY_SCOPE_AGENT);
      __hip_atomic_fetch_or(badAT, 1u, __ATOMIC_RELAXED, __HIP_MEMORY_SCOPE_AGENT);
    }
    unsigned magicN = 0xBEEF0000u | (unsigned)g;
    if (sub == 0){
      asm volatile("global_store_dword %0, %1, off sc0\n\t"
                   "s_waitcnt vmcnt(0)\n\t"
                   "global_store_dword %2, %3, off sc0"
                   :: "v"(ntw), "v"(magicN), "v"(ntarmed), "v"(1u) : "memory");
    }
    int okN = 0;
    for (int i = 0; i < (1 << 14); ++i){
      if (ld1_nt(ntarmed) == 1u){ okN = (ld1_nt(ntw) == magicN); break; }
      if (i > 8) __builtin_amdgcn_s_sleep(1);
    }
    if (!okN) __hip_atomic_fetch_or(badNT, 1u, __ATOMIC_RELAXED, __HIP_MEMORY_SCOPE_AGENT);
    __hip_atomic_fetch_add(arrive2, 1u, __ATOMIC_ACQ_REL, __HIP_MEMORY_SCOPE_AGENT);
    int t2 = 0;
    for (int i = 0; i < (1 << 20); ++i){
      if (__hip_atomic_load(arrive2, __ATOMIC_ACQUIRE, __HIP_MEMORY_SCOPE_AGENT) >= 192u){ t2 = 1; break; }
      __builtin_amdgcn_s_sleep(2);
    }
    if (!t2){
      __hip_atomic_fetch_or(badNT, 1u, __ATOMIC_RELAXED, __HIP_MEMORY_SCOPE_AGENT);
      __hip_atomic_fetch_or(badAT, 1u, __ATOMIC_RELAXED, __HIP_MEMORY_SCOPE_AGENT);
    }
    unsigned magicA = 0xCAFE0000u | (unsigned)g;
    if (sub == 0){
      asm volatile("global_store_dword %0, %1, off sc0\n\t"
                   "s_waitcnt vmcnt(0)" :: "v"(atw), "v"(magicA) : "memory");
      atom_inc(atarmed);
    }
    int okA = 0;
    for (int i = 0; i < (1 << 15); ++i){
      if (atom_poll(atarmed) >= 1u){ okA = (ld1_sc0(atw) == magicA); break; }
      if (i > 16) __builtin_amdgcn_s_sleep(1);
    }
    if (!okA) __hip_atomic_fetch_or(badAT, 1u, __ATOMIC_RELAXED, __HIP_MEMORY_SCOPE_AGENT);
    __hip_atomic_fetch_add(arrive3, 1u, __ATOMIC_ACQ_REL, __HIP_MEMORY_SCOPE_AGENT);
    int t3 = 0;
    for (int i = 0; i < (1 << 20); ++i){
      if (__hip_atomic_load(arrive3, __ATOMIC_ACQUIRE, __HIP_MEMORY_SCOPE_AGENT) >= 192u){ t3 = 1; break; }
      __builtin_amdgcn_s_sleep(2);
    }
    unsigned bN = __hip_atomic_load(badNT, __ATOMIC_ACQUIRE, __HIP_MEMORY_SCOPE_AGENT);
    unsigned bA = __hip_atomic_load(badAT, __ATOMIC_ACQUIRE, __HIP_MEMORY_SCOPE_AGENT);
    s_mode = (!t3) ? 2 : (bN == 0u ? 0 : (bA == 0u ? 1 : 2));
  }
  __syncthreads();
  const int mode = s_mode;

  // Resident weight slice as MFMA B-fragments: lane holds W[n0+cl][kk*32+kh*8+0..7]
  const float* Wmat = (role == 0) ? Whh0 : (role == 1) ? Wih1 : Whh1;
  short8 wf[32];
  {
    const float* wr = Wmat + (size_t)(n0 + cl)*Hn + kh*8;
#pragma unroll
    for (int kk = 0; kk < 32; ++kk){
      float4 a = *(const float4*)(wr + kk*32);
      float4 b = *(const float4*)(wr + kk*32 + 4);
      short8 v;
      v[0]=(short)f2bf(a.x); v[1]=(short)f2bf(a.y); v[2]=(short)f2bf(a.z); v[3]=(short)f2bf(a.w);
      v[4]=(short)f2bf(b.x); v[5]=(short)f2bf(b.y); v[6]=(short)f2bf(b.z); v[7]=(short)f2bf(b.w);
      wf[kk] = v;
    }
  }

  if (mode == 0 && allowPoison)
    rnn_body<0,true >(role, g, slot, tid, w, lane, cl, kh, lrow, pre0_ro, h1base, pre1base, h2base,
                      bias1, FCA0, FCA1, FCB, FCC, FLA, FLB, FLC, FNA, FNB, FNC, wf, hl, outl);
  else if (mode == 0)
    rnn_body<0,false>(role, g, slot, tid, w, lane, cl, kh, lrow, pre0_ro, h1base, pre1base, h2base,
                      bias1, FCA0, FCA1, FCB, FCC, FLA, FLB, FLC, FNA, FNB, FNC, wf, hl, outl);
  else if (mode == 1)
    rnn_body<1,false>(role, g, slot, tid, w, lane, cl, kh, lrow, pre0_ro, h1base, pre1base, h2base,
                      bias1, FCA0, FCA1, FCB, FCC, FLA, FLB, FLC, FNA, FNB, FNC, wf, hl, outl);
  else
    rnn_body<2,false>(role, g, slot, tid, w, lane, cl, kh, lrow, pre0_ro, h1base, pre1base, h2base,
                      bias1, FCA0, FCA1, FCB, FCC, FLA, FLB, FLC, FNA, FNB, FNC, wf, hl, outl);
}

// ---------------- FC head: out[b][o] = h2[b][T-1][:] . Wfc[o][:] + bfc[o] ----------------
__global__ void fc_k(const unsigned short* __restrict__ h2base,
                     const float* __restrict__ Wfc, const float* __restrict__ bfc,
                     float* __restrict__ out)
{
  int gw = (blockIdx.x * blockDim.x + threadIdx.x) >> 6;
  int lane = threadIdx.x & 63;
  int b = gw >> 7, o = gw & 127;
  const unsigned short* tile = h2base + ((size_t)(Tn-1)*8 + (b>>3))*8192;
  int r = b & 7;
  const float* wr = Wfc + (size_t)o*Hn;
  float s = 0.f;
  for (int k = lane; k < Hn; k += 64)
    s += bf2f(tile[((k>>3)*8 + r)*8 + (k&7)]) * wr[k];
#pragma unroll
  for (int off = 32; off > 0; off >>= 1) s += __shfl_down(s, off, 64);
  if (lane == 0) out[b*OUTn + o] = s + bfc[o];
}

// ---------------- host ----------------
extern "C" void kernel_launch(void* const* d_in, const int* in_sizes, int n_in,
                              void* d_out, int out_size, void* d_ws, size_t ws_size,
                              hipStream_t stream)
{
  const float* x    = (const float*)d_in[0];
  const float* Wih0 = (const float*)d_in[1];
  const float* Whh0 = (const float*)d_in[2];
  const float* bih0 = (const float*)d_in[3];
  const float* bhh0 = (const float*)d_in[4];
  const float* Wih1 = (const float*)d_in[5];
  const float* Whh1 = (const float*)d_in[6];
  const float* bih1 = (const float*)d_in[7];
  const float* bhh1 = (const float*)d_in[8];
  const float* Wfc  = (const float*)d_in[9];
  const float* bfc  = (const float*)d_in[10];
  float* out = (float*)d_out;

  const size_t nP  = (size_t)Bn*Tn*Hn;           // pre0 elems (h2 tiles alias in poison mode)
  const size_t nH1 = (size_t)(Tn+2)*8*8192;      // h1 tiles
  const size_t nT  = (size_t)Tn*8*8192;          // pre1 tiles
  const size_t nW  = (size_t)Hn*DINn;

  // poison layout requirement (~203 MB): pre0(+h2) + h1 + pre1 + weights + biases + ctrs
  size_t needP = (nP + nH1 + nT + nW)*2 + 2*Hn*sizeof(float) + 8192*sizeof(unsigned);
  int poison = (ws_size >= needP + 4096) ? 1 : 0;

  unsigned short* bufP  = (unsigned short*)d_ws;                    // pre0 [T][B][H]
  unsigned short* h1buf = bufP  + nP;                               // (T+2) tiles
  unsigned short* pre1b;
  unsigned short* h2b = bufP;                                       // h2 aliases pre0 blocks
  unsigned short* wih0b;
  if (poison){
    pre1b = h1buf + nH1;                                            // T tiles (poisoned)
    wih0b = pre1b + nT;
  } else {
    pre1b = h1buf;                                                  // aliased (r14)
    wih0b = h1buf + nH1;
  }
  float* bias0 = (float*)(wih0b + nW);
  float* bias1 = bias0 + Hn;
  unsigned int* ctrs = (unsigned int*)(bias1 + Hn);                 // 4096 uints

  hipMemsetAsync(ctrs, 0, 4096*sizeof(unsigned int), stream);
  if (poison){
    hipMemsetAsync(h1buf, 0xFF, nH1*2, stream);
    hipMemsetAsync(pre1b, 0xFF, nT*2, stream);
  }

  cvt_bf16x8<<<256, 256, 0, stream>>>(Wih0, wih0b, (long long)(nW/8));
  bias_combine<<<4, 256, 0, stream>>>(bih0, bhh0, bias0, bih1, bhh1, bias1);

  // pre0 = x @ Wih0^T + bias0, written as [T][B][H]
  dim3 g1(Hn/128, (Bn*Tn)/128);
  gemm_pre0<<<g1, 256, 0, stream>>>(x, wih0b, bias0, bufP, Hn, DINn);

  // fused 3-stage pipeline (poison data-flag protocol when ws permits; NT/ATOM/MALL fallback)
  rnn_fused<<<192, 512, 0, stream>>>(bufP, h1buf, pre1b, h2b,
                                     Whh0, Wih1, Whh1, bias1, ctrs, poison);

  // FC head from h2(T-1)
  fc_k<<<2048, 256, 0, stream>>>(h2b, Wfc, bfc, out);
}

// Round 18
// 1147.080 us; speedup vs baseline: 1.1331x; 1.1331x over previous
//
#include <hip/hip_runtime.h>
#include <stdint.h>
#include <stddef.h>

// Problem dims
#define Bn   64
#define Tn   512
#define DINn 512
#define Hn   1024
#define OUTn 128

typedef __attribute__((ext_vector_type(4))) float f32x4;
typedef __attribute__((ext_vector_type(8))) short short8;
typedef __attribute__((ext_vector_type(4))) unsigned int u32x4;

__device__ __forceinline__ unsigned short f2bf(float f){
  unsigned int x = __builtin_bit_cast(unsigned int, f);
  x += 0x7fffu + ((x >> 16) & 1u);           // RNE (values bounded, no NaN/inf)
  return (unsigned short)(x >> 16);
}
__device__ __forceinline__ float bf2f(unsigned short u){
  return __builtin_bit_cast(float, (unsigned int)u << 16);
}
__device__ __forceinline__ float tanh_fast(float v){
  float e = __expf(2.0f * v);
  return 1.0f - 2.0f / (e + 1.0f);
}

// ---- protocol primitives (r12-proven) ----
// MODE 0 (NT): XCD-local flags. Producer: sc0 stores (local L2); consumer: nt loads
//   (no L1 allocation -> repeated polls see L2 updates). Runtime self-tested.
//   r14: per-WAVE detect+stage — wave w polls flag word w, stages slice w (2KB).
// MODE 1 (ATOM): r9-proven. Flags via MALL atomics; data sc0 at read-once addresses.
// MODE 2 (MALL): r4-proven. Everything sc0 sc1.
template<bool FAST>
__device__ __forceinline__ void st16(unsigned short* p, u32x4 v){
  if constexpr (FAST)
    asm volatile("global_store_dwordx4 %0, %1, off sc0" :: "v"(p), "v"(v) : "memory");
  else
    asm volatile("global_store_dwordx4 %0, %1, off sc0 sc1" :: "v"(p), "v"(v) : "memory");
}
__device__ __forceinline__ unsigned atom_poll(unsigned int* p){
  unsigned old, zero = 0;
  asm volatile("global_atomic_add %0, %1, %2, off sc0\n\t"
               "s_waitcnt vmcnt(0)"
               : "=&v"(old) : "v"(p), "v"(zero) : "memory");
  return old;
}
__device__ __forceinline__ void atom_poll2(unsigned int* p1, unsigned int* p2,
                                           unsigned &v1, unsigned &v2){
  unsigned zero = 0;
  asm volatile("global_atomic_add %0, %2, %4, off sc0\n\t"
               "global_atomic_add %1, %3, %4, off sc0\n\t"
               "s_waitcnt vmcnt(0)"
               : "=&v"(v1), "=&v"(v2)
               : "v"(p1), "v"(p2), "v"(zero) : "memory");
}
__device__ __forceinline__ void atom_inc(unsigned int* p){
  unsigned one = 1;
  asm volatile("global_atomic_add %0, %1, off" :: "v"(p), "v"(one) : "memory");
}
__device__ __forceinline__ unsigned ld1_sc0(const unsigned int* p){
  unsigned v;
  asm volatile("global_load_dword %0, %1, off sc0\n\t"
               "s_waitcnt vmcnt(0)" : "=&v"(v) : "v"(p) : "memory");
  return v;
}
__device__ __forceinline__ unsigned ld1_nt(const unsigned int* p){
  unsigned v;
  asm volatile("global_load_dword %0, %1, off nt\n\t"
               "s_waitcnt vmcnt(0)" : "=&v"(v) : "v"(p) : "memory");
  return v;
}
__device__ __forceinline__ void ld2_nt(const unsigned int* p1, const unsigned int* p2,
                                       unsigned &v1, unsigned &v2){
  asm volatile("global_load_dword %0, %2, off nt\n\t"
               "global_load_dword %1, %3, off nt\n\t"
               "s_waitcnt vmcnt(0)"
               : "=&v"(v1), "=&v"(v2) : "v"(p1), "v"(p2) : "memory");
}
__device__ __forceinline__ unsigned umin4(u32x4 a){
  unsigned m0 = a[0] < a[1] ? a[0] : a[1];
  unsigned m1 = a[2] < a[3] ? a[2] : a[3];
  return m0 < m1 ? m0 : m1;
}
__device__ __forceinline__ unsigned ld_line8_slow(const unsigned int* p){
  u32x4 a, b;
  asm volatile("global_load_dwordx4 %0, %2, off sc0 sc1\n\t"
               "global_load_dwordx4 %1, %3, off sc0 sc1\n\t"
               "s_waitcnt vmcnt(0)"
               : "=&v"(a), "=&v"(b) : "v"(p), "v"(p + 4) : "memory");
  unsigned ma = umin4(a), mb = umin4(b);
  return ma < mb ? ma : mb;
}
// Bounded waits. Worst case returns late -> visibly wrong, never a hang.
__device__ __forceinline__ void waitw_nt(const unsigned int* p, unsigned want){
  if (!want) return;
  for (int i = 0; i < (1 << 16); ++i){
    if (ld1_nt(p) >= want) return;
    if (i > 16) __builtin_amdgcn_s_sleep(1);
  }
}
__device__ __forceinline__ void waitw_nt2(const unsigned int* p1, unsigned w1,
                                          const unsigned int* p2, unsigned w2){
  if (!w1){ waitw_nt(p2, w2); return; }
  for (int i = 0; i < (1 << 16); ++i){
    unsigned v1, v2;
    ld2_nt(p1, p2, v1, v2);
    if (v1 >= w1 && v2 >= w2) return;
    if (i > 16) __builtin_amdgcn_s_sleep(1);
  }
}
template<bool FAST>
__device__ __forceinline__ void wait_one(unsigned int* fc, unsigned int* fl, unsigned wfast, unsigned wslow){
  if constexpr (FAST){
    if (!wfast) return;
    for (int i = 0; i < (1 << 16); ++i){
      if (atom_poll(fc) >= wfast) return;
      if (i > 8) __builtin_amdgcn_s_sleep(1);
    }
  } else {
    if (!wslow) return;
    for (int i = 0; i < (1 << 16); ++i){
      if (ld_line8_slow(fl) >= wslow) return;
      if (i > 16) __builtin_amdgcn_s_sleep(1);
    }
  }
}
template<bool FAST>
__device__ __forceinline__ void wait_dual(unsigned int* fc1, unsigned int* fl1, unsigned wf1, unsigned ws1,
                                          unsigned int* fc2, unsigned int* fl2, unsigned wf2, unsigned ws2){
  if constexpr (FAST){
    if (!wf2){ wait_one<true>(fc1, fl1, wf1, ws1); return; }
    for (int i = 0; i < (1 << 16); ++i){
      unsigned v1, v2;
      atom_poll2(fc1, fc2, v1, v2);
      if (v1 >= wf1 && v2 >= wf2) return;
      if (i > 8) __builtin_amdgcn_s_sleep(1);
    }
  } else {
    if (!ws2){ wait_one<false>(fc1, fl1, wf1, ws1); return; }
    for (int i = 0; i < (1 << 16); ++i){
      if (ld_line8_slow(fl1) >= ws1 && ld_line8_slow(fl2) >= ws2) return;
      if (i > 16) __builtin_amdgcn_s_sleep(1);
    }
  }
}

// Per-wave 2KB slice copy global->LDS (slice = 1024 shorts, lane-parallel, sc0).
__device__ __forceinline__ void stage_pw(const unsigned short* src, unsigned short* dst, int lane){
  const unsigned short* p0 = src + lane*8;
  const unsigned short* p1 = p0 + 512;
  u32x4 v0, v1;
  asm volatile("global_load_dwordx4 %0, %2, off sc0\n\t"
               "global_load_dwordx4 %1, %3, off sc0\n\t"
               "s_waitcnt vmcnt(0)"
               : "=&v"(v0), "=&v"(v1) : "v"(p0), "v"(p1) : "memory");
  *(u32x4*)(dst + lane*8) = v0;
  *(u32x4*)(dst + lane*8 + 512) = v1;
}
// Per-wave 2KB slice + 4 bf16 pv loads, one drain.
__device__ __forceinline__ void stage_pw_pv(const unsigned short* src, unsigned short* dst, int lane,
                                            const unsigned short* p4, float* pv){
  const unsigned short* p0 = src + lane*8;
  const unsigned short* p1 = p0 + 512;
  u32x4 v0, v1; unsigned u0,u1,u2,u3;
  asm volatile(
    "global_load_dwordx4 %0, %6, off sc0\n\t"
    "global_load_dwordx4 %1, %7, off sc0\n\t"
    "global_load_ushort %2, %8, off sc0\n\t"
    "global_load_ushort %3, %9, off sc0\n\t"
    "global_load_ushort %4, %10, off sc0\n\t"
    "global_load_ushort %5, %11, off sc0\n\t"
    "s_waitcnt vmcnt(0)"
    : "=&v"(v0),"=&v"(v1),"=&v"(u0),"=&v"(u1),"=&v"(u2),"=&v"(u3)
    : "v"(p0),"v"(p1),"v"(p4),"v"(p4+8),"v"(p4+16),"v"(p4+24) : "memory");
  *(u32x4*)(dst + lane*8) = v0;
  *(u32x4*)(dst + lane*8 + 512) = v1;
  pv[0]=bf2f((unsigned short)u0); pv[1]=bf2f((unsigned short)u1);
  pv[2]=bf2f((unsigned short)u2); pv[3]=bf2f((unsigned short)u3);
}

// Linear 16KB tile copy global->LDS (fallback modes).
template<bool FAST>
__device__ __forceinline__ void stage_lin(const unsigned short* base, unsigned short* hl, int tid){
  const unsigned short* p0 = base + (size_t)tid * 8;
  const unsigned short* p1 = p0 + 4096;
  u32x4 v0, v1;
  if constexpr (FAST)
    asm volatile("global_load_dwordx4 %0, %2, off sc0\n\t"
                 "global_load_dwordx4 %1, %3, off sc0\n\t"
                 "s_waitcnt vmcnt(0)"
                 : "=&v"(v0), "=&v"(v1) : "v"(p0), "v"(p1) : "memory");
  else
    asm volatile("global_load_dwordx4 %0, %2, off sc0 sc1\n\t"
                 "global_load_dwordx4 %1, %3, off sc0 sc1\n\t"
                 "s_waitcnt vmcnt(0)"
                 : "=&v"(v0), "=&v"(v1) : "v"(p0), "v"(p1) : "memory");
  *(u32x4*)((char*)hl + tid * 16) = v0;
  *(u32x4*)((char*)hl + tid * 16 + 8192) = v1;
}
// 4 bf16 scalar loads, chunk-order row walk (stride 8 shorts)
template<bool FAST>
__device__ __forceinline__ void ld4_chunk(const unsigned short* p, float* pv){
  unsigned u0,u1,u2,u3;
  if constexpr (FAST)
    asm volatile("global_load_ushort %0, %4, off sc0\n\t"
                 "global_load_ushort %1, %5, off sc0\n\t"
                 "global_load_ushort %2, %6, off sc0\n\t"
                 "global_load_ushort %3, %7, off sc0\n\t"
                 "s_waitcnt vmcnt(0)"
                 : "=&v"(u0), "=&v"(u1), "=&v"(u2), "=&v"(u3)
                 : "v"(p), "v"(p + 8), "v"(p + 16), "v"(p + 24) : "memory");
  else
    asm volatile("global_load_ushort %0, %4, off sc0 sc1\n\t"
                 "global_load_ushort %1, %5, off sc0 sc1\n\t"
                 "global_load_ushort %2, %6, off sc0 sc1\n\t"
                 "global_load_ushort %3, %7, off sc0 sc1\n\t"
                 "s_waitcnt vmcnt(0)"
                 : "=&v"(u0), "=&v"(u1), "=&v"(u2), "=&v"(u3)
                 : "v"(p), "v"(p + 8), "v"(p + 16), "v"(p + 24) : "memory");
  pv[0] = bf2f((unsigned short)u0); pv[1] = bf2f((unsigned short)u1);
  pv[2] = bf2f((unsigned short)u2); pv[3] = bf2f((unsigned short)u3);
}

// MFMA sweep over K=1024 on chunk-ordered LDS tile (conflict-free, r12-proven).
__device__ __forceinline__ f32x4 mfma_tile(const char* lbase, const short8* wf, int lrow, int kh){
  f32x4 a0 = {0.f,0.f,0.f,0.f}, a1 = a0, a2 = a0, a3 = a0;
  int rb = kh * 128 + lrow * 16;
#pragma unroll
  for (int kk = 0; kk < 8; ++kk)
    a0 = __builtin_amdgcn_mfma_f32_16x16x32_bf16(*(const short8*)(lbase + kk*512 + rb), wf[kk], a0, 0,0,0);
#pragma unroll
  for (int kk = 8; kk < 16; ++kk)
    a1 = __builtin_amdgcn_mfma_f32_16x16x32_bf16(*(const short8*)(lbase + kk*512 + rb), wf[kk], a1, 0,0,0);
#pragma unroll
  for (int kk = 16; kk < 24; ++kk)
    a2 = __builtin_amdgcn_mfma_f32_16x16x32_bf16(*(const short8*)(lbase + kk*512 + rb), wf[kk], a2, 0,0,0);
#pragma unroll
  for (int kk = 24; kk < 32; ++kk)
    a3 = __builtin_amdgcn_mfma_f32_16x16x32_bf16(*(const short8*)(lbase + kk*512 + rb), wf[kk], a3, 0,0,0);
  return (a0 + a1) + (a2 + a3);
}

// ---------------- elementwise f32 -> bf16 ----------------
__global__ void cvt_bf16x8(const float* __restrict__ in, unsigned short* __restrict__ out,
                           long long n8){
  long long i = (long long)blockIdx.x * blockDim.x + threadIdx.x;
  long long stride = (long long)gridDim.x * blockDim.x;
  for (; i < n8; i += stride){
    const float* p = in + i*8;
    float4 a = *(const float4*)p;
    float4 b = *(const float4*)(p+4);
    short8 v;
    v[0]=(short)f2bf(a.x); v[1]=(short)f2bf(a.y); v[2]=(short)f2bf(a.z); v[3]=(short)f2bf(a.w);
    v[4]=(short)f2bf(b.x); v[5]=(short)f2bf(b.y); v[6]=(short)f2bf(b.z); v[7]=(short)f2bf(b.w);
    *(short8*)(out + i*8) = v;
  }
}

__global__ void bias_combine(const float* __restrict__ a, const float* __restrict__ b, float* __restrict__ o,
                             const float* __restrict__ c, const float* __restrict__ d, float* __restrict__ p){
  int i = blockIdx.x * blockDim.x + threadIdx.x;
  if (i < Hn){ o[i] = a[i] + b[i]; p[i] = c[i] + d[i]; }
}

// ---------------- pre0 GEMM: C[t*Bn+b][n] = sum_k x[b*Tn+t][k]*Wih0[n][k] + bias[n] ----------
__launch_bounds__(256, 2)
__global__ void gemm_pre0(const float* __restrict__ Av, const unsigned short* __restrict__ Bm,
                          const float* __restrict__ bias, unsigned short* __restrict__ C,
                          int N, int K)
{
  __shared__ unsigned short lA[128*64];
  __shared__ unsigned short lB[128*64];
  int bn = blockIdx.x, bm = blockIdx.y;
  int m0 = bm*128, n0 = bn*128;
  int tid = threadIdx.x, lane = tid & 63, w = tid >> 6;
  int wm = (w >> 1)*64, wn = (w & 1)*64;
  int cl = lane & 15, kh = lane >> 4;

  f32x4 acc[4][4];
  f32x4 z = {0.f,0.f,0.f,0.f};
#pragma unroll
  for (int i=0;i<4;i++)
#pragma unroll
    for (int j=0;j<4;j++) acc[i][j]=z;

  for (int k0 = 0; k0 < K; k0 += 64){
    __syncthreads();
#pragma unroll
    for (int r = 0; r < 4; ++r){
      int c = r*256 + tid;
      int row = c >> 3, cof = (c & 7)*8;
      const float* ap = Av + (size_t)(m0+row)*K + k0 + cof;
      float4 a = *(const float4*)ap;
      float4 b = *(const float4*)(ap+4);
      short8 v;
      v[0]=(short)f2bf(a.x); v[1]=(short)f2bf(a.y); v[2]=(short)f2bf(a.z); v[3]=(short)f2bf(a.w);
      v[4]=(short)f2bf(b.x); v[5]=(short)f2bf(b.y); v[6]=(short)f2bf(b.z); v[7]=(short)f2bf(b.w);
      *(short8*)&lA[row*64 + cof] = v;
      const unsigned short* bp = Bm + (size_t)(n0+row)*K + k0 + cof;
      *(short8*)&lB[row*64 + cof] = *(const short8*)bp;
    }
    __syncthreads();
#pragma unroll
    for (int kk = 0; kk < 2; ++kk){
      int kb = kk*32 + kh*8;
      short8 af[4], bfr[4];
#pragma unroll
      for (int i=0;i<4;i++) af[i]  = *(const short8*)&lA[(wm + i*16 + cl)*64 + kb];
#pragma unroll
      for (int j=0;j<4;j++) bfr[j] = *(const short8*)&lB[(wn + j*16 + cl)*64 + kb];
#pragma unroll
      for (int i=0;i<4;i++)
#pragma unroll
        for (int j=0;j<4;j++)
          acc[i][j] = __builtin_amdgcn_mfma_f32_16x16x32_bf16(af[i], bfr[j], acc[i][j], 0,0,0);
    }
  }
#pragma unroll
  for (int j=0;j<4;j++){
    int n = n0 + wn + j*16 + cl;
    float bs = bias[n];
#pragma unroll
    for (int i=0;i<4;i++){
      int mr = m0 + wm + i*16 + kh*4;
#pragma unroll
      for (int e=0;e<4;e++){
        int m = mr + e;                       // m = b*Tn + t
        int b = m >> 9, t = m & (Tn-1);
        C[((size_t)t*Bn + b)*N + n] = f2bf(acc[i][j][e] + bs);
      }
    }
  }
}

// ---------------- fused 3-stage recurrence (r12 protocol; MODE0 per-wave detect) ----------------
// 192 wgs, g = bx&7 (one XCD, runtime-verified); sub = bx>>3: role = sub>>3
// (0:L0-rec, 1:pre1-GEMV, 2:L1-rec), slot = sub&7 -> cols [128*slot,+128).
// Group owns batches [8g,8g+8). Chunk-ordered 16KB tiles; slot s's slice = contiguous
// 2KB at tile+s*1024 shorts. Aliasing (read-once-after-flag):
//   h1(t)->tile t+2; pre1(t)->tile t; h2(t)->pre0 slice t.
// MODE0: wave w polls flag word w, stages slice w -> no B1, decentralized detect.
template<int MODE>
__device__ __forceinline__ void rnn_body(
    int role, int g, int slot, int tid, int w, int lane, int cl, int kh, int lrow,
    const unsigned short* pre0, unsigned short* bufP, unsigned short* h1buf,
    const float* bias1,
    unsigned int* FCA0, unsigned int* FCA1, unsigned int* FCB, unsigned int* FCC,
    unsigned int* FLA, unsigned int* FLB, unsigned int* FLC,
    unsigned int* FNA, unsigned int* FNB, unsigned int* FNC,
    const short8* wf, unsigned short* hl, unsigned short* outl)
{
  constexpr bool FAST = (MODE < 2);
  const char* lbase = (const char*)hl;
  int n0 = slot*128 + w*16;
  int olocal = w*128 + ((cl>>3)*8 + kh*4)*8 + (cl&7);    // j stride 8 shorts
  int khc = kh & 1;
  unsigned int* myFL = ((role == 0) ? FLA : (role == 1) ? FLB : FLC) + slot;
  unsigned int* myFN = ((role == 0) ? FNA : (role == 1) ? FNB : FNC) + slot;

  for (int t = 0; t < Tn; ++t){
    float pv[4] = {0.f,0.f,0.f,0.f};
    if (role == 0 && kh < 2){            // prefetch pre0 (plain cached; slice immutable here)
      const unsigned short* pp = pre0 + ((size_t)t*Bn + g*8 + kh*4)*Hn + n0 + cl;
#pragma unroll
      for (int j=0;j<4;j++) pv[j] = bf2f(pp[(size_t)j*Hn]);
    }
    bool staged = true;
    if constexpr (MODE == 0){
      // ---- per-wave detect + slice stage (no B1) ----
      if (role == 0){
        if (t > 0){
          waitw_nt(FNA + w, (unsigned)t);
          stage_pw(h1buf + ((size_t)(t+1)*8 + g)*8192 + w*1024, hl + w*1024, lane);
        } else staged = false;
      } else if (role == 1){
        waitw_nt(FNA + w, (unsigned)(t+1));
        stage_pw(h1buf + ((size_t)(t+2)*8 + g)*8192 + w*1024, hl + w*1024, lane);
      } else {
        const unsigned short* pA = h1buf + ((size_t)t*8 + g)*8192 + slot*1024
                                   + ((w*16+cl)>>3)*64 + khc*32 + (cl&7);   // pre1(t), own cols
        if (t > 0){
          waitw_nt2(FNC + w, (unsigned)t, FNB + slot, (unsigned)(t+1));
          stage_pw_pv(bufP + ((size_t)(t-1)*Bn + g*8)*Hn + w*1024, hl + w*1024, lane, pA, pv);
        } else {
          staged = false;
          waitw_nt(FNB + slot, 1u);
          ld4_chunk<true>(pA, pv);
        }
      }
    } else {
      // ---- fallback modes: centralized tid0 wait + B1 + full stage (r12/r9/r4-proven) ----
      if (tid == 0){
        if (role == 0)      wait_one <FAST>(FCA0, FLA, 8u*(unsigned)t, (unsigned)t);
        else if (role == 1) wait_one <FAST>(FCA1, FLA, 8u*(unsigned)(t+1), (unsigned)(t+1));
        else                wait_dual<FAST>(FCB, FLB, 8u*(unsigned)(t+1), (unsigned)(t+1),
                                            FCC, FLC, 8u*(unsigned)t, (unsigned)t);
      }
      __syncthreads();                                             // B1
      if (role == 0){
        if (t > 0) stage_lin<FAST>(h1buf + ((size_t)(t+1)*8 + g)*8192, hl, tid);
        else staged = false;
      } else if (role == 1){
        stage_lin<FAST>(h1buf + ((size_t)(t+2)*8 + g)*8192, hl, tid);
      } else {
        if (kh < 2)
          ld4_chunk<FAST>(h1buf + ((size_t)t*8 + g)*8192 + slot*1024 + ((w*16+cl)>>3)*64 + kh*32 + (cl&7), pv);
        if (t > 0) stage_lin<FAST>(bufP + ((size_t)(t-1)*Bn + g*8)*Hn, hl, tid);
        else staged = false;
      }
    }
    __syncthreads();                                               // B2 (tile staged)
    // ---- compute ----
    f32x4 acc = {0.f,0.f,0.f,0.f};
    if (staged) acc = mfma_tile(lbase, wf, lrow, kh);
    // ---- transpose to wave-local LDS, vector-store tile slice ----
    if (kh < 2){
      float bs = (role == 1) ? bias1[n0 + cl] : 0.f;
#pragma unroll
      for (int j=0;j<4;j++){
        float v = acc[j] + pv[j] + bs;
        if (role != 1) v = tanh_fast(v);
        outl[olocal + j*8] = f2bf(v);
      }
    }
    // same-wave cross-lane via LDS (ds ordering within wave), then vector store
    unsigned short* tile;
    if (role == 0)      tile = h1buf + ((size_t)(t+2)*8 + g)*8192;
    else if (role == 1) tile = h1buf + ((size_t)t*8 + g)*8192;
    else                tile = bufP + ((size_t)t*Bn + g*8)*Hn;
    if (lane < 16){
      u32x4 v = *(const u32x4*)(outl + w*128 + lane*8);
      st16<FAST>(tile + slot*1024 + (w*16 + lane)*8, v);
    }
    asm volatile("s_waitcnt vmcnt(0)" ::: "memory");
    __syncthreads();                                               // B3 (all stores at L2/MALL)
    if (tid == 0){
      if constexpr (MODE == 0){
        asm volatile("global_store_dword %0, %1, off sc0" :: "v"(myFN), "v"((unsigned)(t+1)) : "memory");
      } else if constexpr (MODE == 1){
        if (role == 0){ atom_inc(FCA0); atom_inc(FCA1); }
        else if (role == 1) atom_inc(FCB);
        else atom_inc(FCC);
      } else {
        asm volatile("global_store_dword %0, %1, off sc0 sc1" :: "v"(myFL), "v"((unsigned)(t+1)) : "memory");
      }
    }
  }
}

__launch_bounds__(512, 2)
__global__ void rnn_fused(const unsigned short* __restrict__ pre0_ro,
                          unsigned short* __restrict__ bufP,
                          unsigned short* __restrict__ h1buf,
                          const float* __restrict__ Whh0,
                          const float* __restrict__ Wih1,
                          const float* __restrict__ Whh1,
                          const float* __restrict__ bias1,
                          unsigned int* ctrs)
{
  __shared__ __align__(16) unsigned short hl[8192];    // 16KB staged tile (chunk order)
  __shared__ __align__(16) unsigned short outl[1024];  // 2KB, wave-local transpose
  __shared__ int s_mode;
  int bx = blockIdx.x;
  int g = bx & 7;
  int sub = bx >> 3;
  int role = sub >> 3, slot = sub & 7;
  int tid = threadIdx.x, lane = tid & 63, w = tid >> 6;
  int n0 = slot*128 + w*16;
  int cl = lane & 15, kh = lane >> 4, lrow = cl & 7;
  unsigned int* FLA = ctrs + (0*8 + g)*32;   // MALL flag lines (8 words each)
  unsigned int* FLB = ctrs + (1*8 + g)*32;
  unsigned int* FLC = ctrs + (2*8 + g)*32;
  unsigned int* arrive1 = ctrs + 768;
  unsigned int* badAT   = ctrs + 772;
  unsigned int* arrive2 = ctrs + 776;
  unsigned int* badNT   = ctrs + 780;
  unsigned int* arrive3 = ctrs + 784;
  unsigned int* FCA0 = ctrs + 1536 + (0*8 + g)*32;  // MODE1 counters (128B-spaced)
  unsigned int* FCB  = ctrs + 1536 + (1*8 + g)*32;
  unsigned int* FCC  = ctrs + 1536 + (2*8 + g)*32;
  unsigned int* FCA1 = ctrs + 1536 + (3*8 + g)*32;
  unsigned int* FNA = ctrs + 2560 + (0*8 + g)*32;   // MODE0 NT flag lines
  unsigned int* FNB = ctrs + 2560 + (1*8 + g)*32;
  unsigned int* FNC = ctrs + 2560 + (2*8 + g)*32;

  // ---- one-time self-tests: NT sequence, then ATOM sequence; consensus via bad flags ----
  if (tid == 0){
    int xcc;
    asm volatile("s_getreg_b32 %0, hwreg(HW_REG_XCC_ID)" : "=s"(xcc));
    unsigned int* atw = ctrs + 1024 + g*32;  unsigned int* atarmed = atw + 16;
    unsigned int* ntw = ctrs + 3328 + g*32;  unsigned int* ntarmed = ntw + 16;
    if (xcc != g){
      __hip_atomic_fetch_or(badNT, 1u, __ATOMIC_RELAXED, __HIP_MEMORY_SCOPE_AGENT);
      __hip_atomic_fetch_or(badAT, 1u, __ATOMIC_RELAXED, __HIP_MEMORY_SCOPE_AGENT);
    }
    unsigned pr = ld1_nt(ntw) + ld1_nt(ntarmed);   // prime NT lines (stale-L1 hazard probe)
    asm volatile("" :: "v"(pr));
    __hip_atomic_fetch_add(arrive1, 1u, __ATOMIC_ACQ_REL, __HIP_MEMORY_SCOPE_AGENT);
    int t1 = 0;
    for (int i = 0; i < (1 << 20); ++i){
      if (__hip_atomic_load(arrive1, __ATOMIC_ACQUIRE, __HIP_MEMORY_SCOPE_AGENT) >= 192u){ t1 = 1; break; }
      __builtin_amdgcn_s_sleep(2);
    }
    if (!t1){
      __hip_atomic_fetch_or(badNT, 1u, __ATOMIC_RELAXED, __HIP_MEMORY_SCOPE_AGENT);
      __hip_atomic_fetch_or(badAT, 1u, __ATOMIC_RELAXED, __HIP_MEMORY_SCOPE_AGENT);
    }
    unsigned magicN = 0xBEEF0000u | (unsigned)g;
    if (sub == 0){
      asm volatile("global_store_dword %0, %1, off sc0\n\t"
                   "s_waitcnt vmcnt(0)\n\t"
                   "global_store_dword %2, %3, off sc0"
                   :: "v"(ntw), "v"(magicN), "v"(ntarmed), "v"(1u) : "memory");
    }
    int okN = 0;
    for (int i = 0; i < (1 << 14); ++i){
      if (ld1_nt(ntarmed) == 1u){ okN = (ld1_nt(ntw) == magicN); break; }
      if (i > 8) __builtin_amdgcn_s_sleep(1);
    }
    if (!okN) __hip_atomic_fetch_or(badNT, 1u, __ATOMIC_RELAXED, __HIP_MEMORY_SCOPE_AGENT);
    __hip_atomic_fetch_add(arrive2, 1u, __ATOMIC_ACQ_REL, __HIP_MEMORY_SCOPE_AGENT);
    int t2 = 0;
    for (int i = 0; i < (1 << 20); ++i){
      if (__hip_atomic_load(arrive2, __ATOMIC_ACQUIRE, __HIP_MEMORY_SCOPE_AGENT) >= 192u){ t2 = 1; break; }
      __builtin_amdgcn_s_sleep(2);
    }
    if (!t2){
      __hip_atomic_fetch_or(badNT, 1u, __ATOMIC_RELAXED, __HIP_MEMORY_SCOPE_AGENT);
      __hip_atomic_fetch_or(badAT, 1u, __ATOMIC_RELAXED, __HIP_MEMORY_SCOPE_AGENT);
    }
    unsigned magicA = 0xCAFE0000u | (unsigned)g;
    if (sub == 0){
      asm volatile("global_store_dword %0, %1, off sc0\n\t"
                   "s_waitcnt vmcnt(0)" :: "v"(atw), "v"(magicA) : "memory");
      atom_inc(atarmed);
    }
    int okA = 0;
    for (int i = 0; i < (1 << 15); ++i){
      if (atom_poll(atarmed) >= 1u){ okA = (ld1_sc0(atw) == magicA); break; }
      if (i > 16) __builtin_amdgcn_s_sleep(1);
    }
    if (!okA) __hip_atomic_fetch_or(badAT, 1u, __ATOMIC_RELAXED, __HIP_MEMORY_SCOPE_AGENT);
    __hip_atomic_fetch_add(arrive3, 1u, __ATOMIC_ACQ_REL, __HIP_MEMORY_SCOPE_AGENT);
    int t3 = 0;
    for (int i = 0; i < (1 << 20); ++i){
      if (__hip_atomic_load(arrive3, __ATOMIC_ACQUIRE, __HIP_MEMORY_SCOPE_AGENT) >= 192u){ t3 = 1; break; }
      __builtin_amdgcn_s_sleep(2);
    }
    unsigned bN = __hip_atomic_load(badNT, __ATOMIC_ACQUIRE, __HIP_MEMORY_SCOPE_AGENT);
    unsigned bA = __hip_atomic_load(badAT, __ATOMIC_ACQUIRE, __HIP_MEMORY_SCOPE_AGENT);
    s_mode = (!t3) ? 2 : (bN == 0u ? 0 : (bA == 0u ? 1 : 2));
  }
  __syncthreads();
  const int mode = s_mode;

  // Resident weight slice as MFMA B-fragments: lane holds W[n0+cl][kk*32+kh*8+0..7]
  const float* Wmat = (role == 0) ? Whh0 : (role == 1) ? Wih1 : Whh1;
  short8 wf[32];
  {
    const float* wr = Wmat + (size_t)(n0 + cl)*Hn + kh*8;
#pragma unroll
    for (int kk = 0; kk < 32; ++kk){
      float4 a = *(const float4*)(wr + kk*32);
      float4 b = *(const float4*)(wr + kk*32 + 4);
      short8 v;
      v[0]=(short)f2bf(a.x); v[1]=(short)f2bf(a.y); v[2]=(short)f2bf(a.z); v[3]=(short)f2bf(a.w);
      v[4]=(short)f2bf(b.x); v[5]=(short)f2bf(b.y); v[6]=(short)f2bf(b.z); v[7]=(short)f2bf(b.w);
      wf[kk] = v;
    }
  }

  if (mode == 0)
    rnn_body<0>(role, g, slot, tid, w, lane, cl, kh, lrow, pre0_ro, bufP, h1buf,
                bias1, FCA0, FCA1, FCB, FCC, FLA, FLB, FLC, FNA, FNB, FNC, wf, hl, outl);
  else if (mode == 1)
    rnn_body<1>(role, g, slot, tid, w, lane, cl, kh, lrow, pre0_ro, bufP, h1buf,
                bias1, FCA0, FCA1, FCB, FCC, FLA, FLB, FLC, FNA, FNB, FNC, wf, hl, outl);
  else
    rnn_body<2>(role, g, slot, tid, w, lane, cl, kh, lrow, pre0_ro, bufP, h1buf,
                bias1, FCA0, FCA1, FCB, FCC, FLA, FLB, FLC, FNA, FNB, FNC, wf, hl, outl);
}

// ---------------- FC head: out[b][o] = h2[b][T-1][:] . Wfc[o][:] + bfc[o] ----------------
__global__ void fc_k(const unsigned short* __restrict__ bufP,
                     const float* __restrict__ Wfc, const float* __restrict__ bfc,
                     float* __restrict__ out)
{
  int gw = (blockIdx.x * blockDim.x + threadIdx.x) >> 6;
  int lane = threadIdx.x & 63;
  int b = gw >> 7, o = gw & 127;
  // h2(T-1) lives in pre0 slice T-1, group tile (b>>3), chunk-ordered
  const unsigned short* tile = bufP + ((size_t)(Tn-1)*Bn + (b & ~7))*Hn;
  int r = b & 7;
  const float* wr = Wfc + (size_t)o*Hn;
  float s = 0.f;
  for (int k = lane; k < Hn; k += 64)
    s += bf2f(tile[((k>>3)*8 + r)*8 + (k&7)]) * wr[k];
#pragma unroll
  for (int off = 32; off > 0; off >>= 1) s += __shfl_down(s, off, 64);
  if (lane == 0) out[b*OUTn + o] = s + bfc[o];
}

// ---------------- host ----------------
extern "C" void kernel_launch(void* const* d_in, const int* in_sizes, int n_in,
                              void* d_out, int out_size, void* d_ws, size_t ws_size,
                              hipStream_t stream)
{
  const float* x    = (const float*)d_in[0];
  const float* Wih0 = (const float*)d_in[1];
  const float* Whh0 = (const float*)d_in[2];
  const float* bih0 = (const float*)d_in[3];
  const float* bhh0 = (const float*)d_in[4];
  const float* Wih1 = (const float*)d_in[5];
  const float* Whh1 = (const float*)d_in[6];
  const float* bih1 = (const float*)d_in[7];
  const float* bhh1 = (const float*)d_in[8];
  const float* Wfc  = (const float*)d_in[9];
  const float* bfc  = (const float*)d_in[10];
  float* out = (float*)d_out;

  // workspace (bf16 elements)
  unsigned short* bufP  = (unsigned short*)d_ws;                    // pre0 [T][B][H]; h2 aliases slices
  unsigned short* h1buf = bufP  + (size_t)Bn*Tn*Hn;                 // (T+2)*8 chunk-ordered 16KB tiles
  unsigned short* wih0b = h1buf + (size_t)(Tn+2)*8*8192;            // 1MiB
  float* bias0 = (float*)(wih0b + (size_t)Hn*DINn);
  float* bias1 = bias0 + Hn;
  unsigned int* ctrs = (unsigned int*)(bias1 + Hn);                 // 4096 uints

  hipMemsetAsync(ctrs, 0, 4096*sizeof(unsigned int), stream);

  cvt_bf16x8<<<256, 256, 0, stream>>>(Wih0, wih0b, (long long)Hn*DINn/8);
  bias_combine<<<4, 256, 0, stream>>>(bih0, bhh0, bias0, bih1, bhh1, bias1);

  // pre0 = x @ Wih0^T + bias0, written as [T][B][H]
  dim3 g1(Hn/128, (Bn*Tn)/128);
  gemm_pre0<<<g1, 256, 0, stream>>>(x, wih0b, bias0, bufP, Hn, DINn);

  // fused 3-stage pipeline (self-tested NT / ATOM / MALL flags; MODE0 per-wave detect)
  rnn_fused<<<192, 512, 0, stream>>>(bufP, bufP, h1buf, Whh0, Wih1, Whh1, bias1, ctrs);

  // FC head from h2(T-1) (aliased into pre0 slice T-1)
  fc_k<<<2048, 256, 0, stream>>>(bufP, Wfc, bfc, out);
}

// Round 19
// 1126.288 us; speedup vs baseline: 1.1540x; 1.0185x over previous
//
#include <hip/hip_runtime.h>
#include <stdint.h>
#include <stddef.h>

// Problem dims
#define Bn   64
#define Tn   512
#define DINn 512
#define Hn   1024
#define OUTn 128

typedef __attribute__((ext_vector_type(4))) float f32x4;
typedef __attribute__((ext_vector_type(8))) short short8;
typedef __attribute__((ext_vector_type(4))) unsigned int u32x4;

__device__ __forceinline__ unsigned short f2bf(float f){
  unsigned int x = __builtin_bit_cast(unsigned int, f);
  x += 0x7fffu + ((x >> 16) & 1u);           // RNE (values bounded, no NaN/inf)
  return (unsigned short)(x >> 16);
}
__device__ __forceinline__ float bf2f(unsigned short u){
  return __builtin_bit_cast(float, (unsigned int)u << 16);
}
__device__ __forceinline__ float tanh_fast(float v){
  float e = __expf(2.0f * v);
  return 1.0f - 2.0f / (e + 1.0f);
}

// ---- protocol primitives ----
// MODE 0 (NT, r14-proven + r19 per-wave publish): XCD-local flags. Producer WAVE w of wg
//   (role,slot) publishes flag word [slot*8+w] after draining ITS OWN sc0 stores — no
//   post-store barrier, no tid0 funnel. Consumers min-poll the producer wg's 8-word line
//   (nt loads bypass L1). hl double-buffered (t&1) so the single B2 barrier suffices.
// MODE 1 (ATOM): r9-proven. Flags via MALL atomics. MODE 2 (MALL): r4-proven, sc0 sc1.
template<bool FAST>
__device__ __forceinline__ void st16(unsigned short* p, u32x4 v){
  if constexpr (FAST)
    asm volatile("global_store_dwordx4 %0, %1, off sc0" :: "v"(p), "v"(v) : "memory");
  else
    asm volatile("global_store_dwordx4 %0, %1, off sc0 sc1" :: "v"(p), "v"(v) : "memory");
}
__device__ __forceinline__ unsigned atom_poll(unsigned int* p){
  unsigned old, zero = 0;
  asm volatile("global_atomic_add %0, %1, %2, off sc0\n\t"
               "s_waitcnt vmcnt(0)"
               : "=&v"(old) : "v"(p), "v"(zero) : "memory");
  return old;
}
__device__ __forceinline__ void atom_poll2(unsigned int* p1, unsigned int* p2,
                                           unsigned &v1, unsigned &v2){
  unsigned zero = 0;
  asm volatile("global_atomic_add %0, %2, %4, off sc0\n\t"
               "global_atomic_add %1, %3, %4, off sc0\n\t"
               "s_waitcnt vmcnt(0)"
               : "=&v"(v1), "=&v"(v2)
               : "v"(p1), "v"(p2), "v"(zero) : "memory");
}
__device__ __forceinline__ void atom_inc(unsigned int* p){
  unsigned one = 1;
  asm volatile("global_atomic_add %0, %1, off" :: "v"(p), "v"(one) : "memory");
}
__device__ __forceinline__ unsigned ld1_sc0(const unsigned int* p){
  unsigned v;
  asm volatile("global_load_dword %0, %1, off sc0\n\t"
               "s_waitcnt vmcnt(0)" : "=&v"(v) : "v"(p) : "memory");
  return v;
}
__device__ __forceinline__ unsigned ld1_nt(const unsigned int* p){
  unsigned v;
  asm volatile("global_load_dword %0, %1, off nt\n\t"
               "s_waitcnt vmcnt(0)" : "=&v"(v) : "v"(p) : "memory");
  return v;
}
__device__ __forceinline__ unsigned umin4(u32x4 a){
  unsigned m0 = a[0] < a[1] ? a[0] : a[1];
  unsigned m1 = a[2] < a[3] ? a[2] : a[3];
  return m0 < m1 ? m0 : m1;
}
__device__ __forceinline__ unsigned ld_line8_nt(const unsigned int* p){
  u32x4 a, b;
  asm volatile("global_load_dwordx4 %0, %2, off nt\n\t"
               "global_load_dwordx4 %1, %3, off nt\n\t"
               "s_waitcnt vmcnt(0)"
               : "=&v"(a), "=&v"(b) : "v"(p), "v"(p + 4) : "memory");
  unsigned ma = umin4(a), mb = umin4(b);
  return ma < mb ? ma : mb;
}
__device__ __forceinline__ unsigned ld_line8_slow(const unsigned int* p){
  u32x4 a, b;
  asm volatile("global_load_dwordx4 %0, %2, off sc0 sc1\n\t"
               "global_load_dwordx4 %1, %3, off sc0 sc1\n\t"
               "s_waitcnt vmcnt(0)"
               : "=&v"(a), "=&v"(b) : "v"(p), "v"(p + 4) : "memory");
  unsigned ma = umin4(a), mb = umin4(b);
  return ma < mb ? ma : mb;
}
// Bounded waits. Worst case returns late -> visibly wrong, never a hang.
__device__ __forceinline__ void wait8_nt(const unsigned int* p, unsigned want){
  if (!want) return;
  for (int i = 0; i < (1 << 16); ++i){
    if (ld_line8_nt(p) >= want) return;
    if (i > 16) __builtin_amdgcn_s_sleep(1);
  }
}
__device__ __forceinline__ void wait8_nt2(const unsigned int* p1, unsigned w1,
                                          const unsigned int* p2, unsigned w2){
  if (!w1){ wait8_nt(p2, w2); return; }
  for (int i = 0; i < (1 << 16); ++i){
    u32x4 a, b, c, d;
    asm volatile("global_load_dwordx4 %0, %4, off nt\n\t"
                 "global_load_dwordx4 %1, %5, off nt\n\t"
                 "global_load_dwordx4 %2, %6, off nt\n\t"
                 "global_load_dwordx4 %3, %7, off nt\n\t"
                 "s_waitcnt vmcnt(0)"
                 : "=&v"(a), "=&v"(b), "=&v"(c), "=&v"(d)
                 : "v"(p1), "v"(p1 + 4), "v"(p2), "v"(p2 + 4) : "memory");
    unsigned m1 = umin4(a) < umin4(b) ? umin4(a) : umin4(b);
    unsigned m2 = umin4(c) < umin4(d) ? umin4(c) : umin4(d);
    if (m1 >= w1 && m2 >= w2) return;
    if (i > 16) __builtin_amdgcn_s_sleep(1);
  }
}
template<bool FAST>
__device__ __forceinline__ void wait_one(unsigned int* fc, unsigned int* fl, unsigned wfast, unsigned wslow){
  if constexpr (FAST){
    if (!wfast) return;
    for (int i = 0; i < (1 << 16); ++i){
      if (atom_poll(fc) >= wfast) return;
      if (i > 8) __builtin_amdgcn_s_sleep(1);
    }
  } else {
    if (!wslow) return;
    for (int i = 0; i < (1 << 16); ++i){
      if (ld_line8_slow(fl) >= wslow) return;
      if (i > 16) __builtin_amdgcn_s_sleep(1);
    }
  }
}
template<bool FAST>
__device__ __forceinline__ void wait_dual(unsigned int* fc1, unsigned int* fl1, unsigned wf1, unsigned ws1,
                                          unsigned int* fc2, unsigned int* fl2, unsigned wf2, unsigned ws2){
  if constexpr (FAST){
    if (!wf2){ wait_one<true>(fc1, fl1, wf1, ws1); return; }
    for (int i = 0; i < (1 << 16); ++i){
      unsigned v1, v2;
      atom_poll2(fc1, fc2, v1, v2);
      if (v1 >= wf1 && v2 >= wf2) return;
      if (i > 8) __builtin_amdgcn_s_sleep(1);
    }
  } else {
    if (!ws2){ wait_one<false>(fc1, fl1, wf1, ws1); return; }
    for (int i = 0; i < (1 << 16); ++i){
      if (ld_line8_slow(fl1) >= ws1 && ld_line8_slow(fl2) >= ws2) return;
      if (i > 16) __builtin_amdgcn_s_sleep(1);
    }
  }
}

// Per-wave 2KB slice copy global->LDS (slice = 1024 shorts, lane-parallel, sc0).
__device__ __forceinline__ void stage_pw(const unsigned short* src, unsigned short* dst, int lane){
  const unsigned short* p0 = src + lane*8;
  const unsigned short* p1 = p0 + 512;
  u32x4 v0, v1;
  asm volatile("global_load_dwordx4 %0, %2, off sc0\n\t"
               "global_load_dwordx4 %1, %3, off sc0\n\t"
               "s_waitcnt vmcnt(0)"
               : "=&v"(v0), "=&v"(v1) : "v"(p0), "v"(p1) : "memory");
  *(u32x4*)(dst + lane*8) = v0;
  *(u32x4*)(dst + lane*8 + 512) = v1;
}
// Per-wave 2KB slice + 4 bf16 pv loads, one drain.
__device__ __forceinline__ void stage_pw_pv(const unsigned short* src, unsigned short* dst, int lane,
                                            const unsigned short* p4, float* pv){
  const unsigned short* p0 = src + lane*8;
  const unsigned short* p1 = p0 + 512;
  u32x4 v0, v1; unsigned u0,u1,u2,u3;
  asm volatile(
    "global_load_dwordx4 %0, %6, off sc0\n\t"
    "global_load_dwordx4 %1, %7, off sc0\n\t"
    "global_load_ushort %2, %8, off sc0\n\t"
    "global_load_ushort %3, %9, off sc0\n\t"
    "global_load_ushort %4, %10, off sc0\n\t"
    "global_load_ushort %5, %11, off sc0\n\t"
    "s_waitcnt vmcnt(0)"
    : "=&v"(v0),"=&v"(v1),"=&v"(u0),"=&v"(u1),"=&v"(u2),"=&v"(u3)
    : "v"(p0),"v"(p1),"v"(p4),"v"(p4+8),"v"(p4+16),"v"(p4+24) : "memory");
  *(u32x4*)(dst + lane*8) = v0;
  *(u32x4*)(dst + lane*8 + 512) = v1;
  pv[0]=bf2f((unsigned short)u0); pv[1]=bf2f((unsigned short)u1);
  pv[2]=bf2f((unsigned short)u2); pv[3]=bf2f((unsigned short)u3);
}

// Linear 16KB tile copy global->LDS (fallback modes).
template<bool FAST>
__device__ __forceinline__ void stage_lin(const unsigned short* base, unsigned short* hl, int tid){
  const unsigned short* p0 = base + (size_t)tid * 8;
  const unsigned short* p1 = p0 + 4096;
  u32x4 v0, v1;
  if constexpr (FAST)
    asm volatile("global_load_dwordx4 %0, %2, off sc0\n\t"
                 "global_load_dwordx4 %1, %3, off sc0\n\t"
                 "s_waitcnt vmcnt(0)"
                 : "=&v"(v0), "=&v"(v1) : "v"(p0), "v"(p1) : "memory");
  else
    asm volatile("global_load_dwordx4 %0, %2, off sc0 sc1\n\t"
                 "global_load_dwordx4 %1, %3, off sc0 sc1\n\t"
                 "s_waitcnt vmcnt(0)"
                 : "=&v"(v0), "=&v"(v1) : "v"(p0), "v"(p1) : "memory");
  *(u32x4*)((char*)hl + tid * 16) = v0;
  *(u32x4*)((char*)hl + tid * 16 + 8192) = v1;
}
// 4 bf16 scalar loads, chunk-order row walk (stride 8 shorts)
template<bool FAST>
__device__ __forceinline__ void ld4_chunk(const unsigned short* p, float* pv){
  unsigned u0,u1,u2,u3;
  if constexpr (FAST)
    asm volatile("global_load_ushort %0, %4, off sc0\n\t"
                 "global_load_ushort %1, %5, off sc0\n\t"
                 "global_load_ushort %2, %6, off sc0\n\t"
                 "global_load_ushort %3, %7, off sc0\n\t"
                 "s_waitcnt vmcnt(0)"
                 : "=&v"(u0), "=&v"(u1), "=&v"(u2), "=&v"(u3)
                 : "v"(p), "v"(p + 8), "v"(p + 16), "v"(p + 24) : "memory");
  else
    asm volatile("global_load_ushort %0, %4, off sc0 sc1\n\t"
                 "global_load_ushort %1, %5, off sc0 sc1\n\t"
                 "global_load_ushort %2, %6, off sc0 sc1\n\t"
                 "global_load_ushort %3, %7, off sc0 sc1\n\t"
                 "s_waitcnt vmcnt(0)"
                 : "=&v"(u0), "=&v"(u1), "=&v"(u2), "=&v"(u3)
                 : "v"(p), "v"(p + 8), "v"(p + 16), "v"(p + 24) : "memory");
  pv[0] = bf2f((unsigned short)u0); pv[1] = bf2f((unsigned short)u1);
  pv[2] = bf2f((unsigned short)u2); pv[3] = bf2f((unsigned short)u3);
}

// MFMA sweep over K=1024 on chunk-ordered LDS tile (conflict-free, r12-proven).
__device__ __forceinline__ f32x4 mfma_tile(const char* lbase, const short8* wf, int lrow, int kh){
  f32x4 a0 = {0.f,0.f,0.f,0.f}, a1 = a0, a2 = a0, a3 = a0;
  int rb = kh * 128 + lrow * 16;
#pragma unroll
  for (int kk = 0; kk < 8; ++kk)
    a0 = __builtin_amdgcn_mfma_f32_16x16x32_bf16(*(const short8*)(lbase + kk*512 + rb), wf[kk], a0, 0,0,0);
#pragma unroll
  for (int kk = 8; kk < 16; ++kk)
    a1 = __builtin_amdgcn_mfma_f32_16x16x32_bf16(*(const short8*)(lbase + kk*512 + rb), wf[kk], a1, 0,0,0);
#pragma unroll
  for (int kk = 16; kk < 24; ++kk)
    a2 = __builtin_amdgcn_mfma_f32_16x16x32_bf16(*(const short8*)(lbase + kk*512 + rb), wf[kk], a2, 0,0,0);
#pragma unroll
  for (int kk = 24; kk < 32; ++kk)
    a3 = __builtin_amdgcn_mfma_f32_16x16x32_bf16(*(const short8*)(lbase + kk*512 + rb), wf[kk], a3, 0,0,0);
  return (a0 + a1) + (a2 + a3);
}

// ---------------- elementwise f32 -> bf16 ----------------
__global__ void cvt_bf16x8(const float* __restrict__ in, unsigned short* __restrict__ out,
                           long long n8){
  long long i = (long long)blockIdx.x * blockDim.x + threadIdx.x;
  long long stride = (long long)gridDim.x * blockDim.x;
  for (; i < n8; i += stride){
    const float* p = in + i*8;
    float4 a = *(const float4*)p;
    float4 b = *(const float4*)(p+4);
    short8 v;
    v[0]=(short)f2bf(a.x); v[1]=(short)f2bf(a.y); v[2]=(short)f2bf(a.z); v[3]=(short)f2bf(a.w);
    v[4]=(short)f2bf(b.x); v[5]=(short)f2bf(b.y); v[6]=(short)f2bf(b.z); v[7]=(short)f2bf(b.w);
    *(short8*)(out + i*8) = v;
  }
}

__global__ void bias_combine(const float* __restrict__ a, const float* __restrict__ b, float* __restrict__ o,
                             const float* __restrict__ c, const float* __restrict__ d, float* __restrict__ p){
  int i = blockIdx.x * blockDim.x + threadIdx.x;
  if (i < Hn){ o[i] = a[i] + b[i]; p[i] = c[i] + d[i]; }
}

// ---------------- pre0 GEMM: C[t*Bn+b][n] = sum_k x[b*Tn+t][k]*Wih0[n][k] + bias[n] ----------
__launch_bounds__(256, 2)
__global__ void gemm_pre0(const float* __restrict__ Av, const unsigned short* __restrict__ Bm,
                          const float* __restrict__ bias, unsigned short* __restrict__ C,
                          int N, int K)
{
  __shared__ unsigned short lA[128*64];
  __shared__ unsigned short lB[128*64];
  int bn = blockIdx.x, bm = blockIdx.y;
  int m0 = bm*128, n0 = bn*128;
  int tid = threadIdx.x, lane = tid & 63, w = tid >> 6;
  int wm = (w >> 1)*64, wn = (w & 1)*64;
  int cl = lane & 15, kh = lane >> 4;

  f32x4 acc[4][4];
  f32x4 z = {0.f,0.f,0.f,0.f};
#pragma unroll
  for (int i=0;i<4;i++)
#pragma unroll
    for (int j=0;j<4;j++) acc[i][j]=z;

  for (int k0 = 0; k0 < K; k0 += 64){
    __syncthreads();
#pragma unroll
    for (int r = 0; r < 4; ++r){
      int c = r*256 + tid;
      int row = c >> 3, cof = (c & 7)*8;
      const float* ap = Av + (size_t)(m0+row)*K + k0 + cof;
      float4 a = *(const float4*)ap;
      float4 b = *(const float4*)(ap+4);
      short8 v;
      v[0]=(short)f2bf(a.x); v[1]=(short)f2bf(a.y); v[2]=(short)f2bf(a.z); v[3]=(short)f2bf(a.w);
      v[4]=(short)f2bf(b.x); v[5]=(short)f2bf(b.y); v[6]=(short)f2bf(b.z); v[7]=(short)f2bf(b.w);
      *(short8*)&lA[row*64 + cof] = v;
      const unsigned short* bp = Bm + (size_t)(n0+row)*K + k0 + cof;
      *(short8*)&lB[row*64 + cof] = *(const short8*)bp;
    }
    __syncthreads();
#pragma unroll
    for (int kk = 0; kk < 2; ++kk){
      int kb = kk*32 + kh*8;
      short8 af[4], bfr[4];
#pragma unroll
      for (int i=0;i<4;i++) af[i]  = *(const short8*)&lA[(wm + i*16 + cl)*64 + kb];
#pragma unroll
      for (int j=0;j<4;j++) bfr[j] = *(const short8*)&lB[(wn + j*16 + cl)*64 + kb];
#pragma unroll
      for (int i=0;i<4;i++)
#pragma unroll
        for (int j=0;j<4;j++)
          acc[i][j] = __builtin_amdgcn_mfma_f32_16x16x32_bf16(af[i], bfr[j], acc[i][j], 0,0,0);
    }
  }
#pragma unroll
  for (int j=0;j<4;j++){
    int n = n0 + wn + j*16 + cl;
    float bs = bias[n];
#pragma unroll
    for (int i=0;i<4;i++){
      int mr = m0 + wm + i*16 + kh*4;
#pragma unroll
      for (int e=0;e<4;e++){
        int m = mr + e;                       // m = b*Tn + t
        int b = m >> 9, t = m & (Tn-1);
        C[((size_t)t*Bn + b)*N + n] = f2bf(acc[i][j][e] + bs);
      }
    }
  }
}

// ---------------- fused 3-stage recurrence (MODE0: per-wave detect + per-wave publish) --------
// 192 wgs, g = bx&7 (one XCD, runtime-verified); sub = bx>>3: role = sub>>3
// (0:L0-rec, 1:pre1-GEMV, 2:L1-rec), slot = sub&7 -> cols [128*slot,+128).
// Chunk-ordered 16KB tiles; slot s's slice = contiguous 2KB at tile+s*1024 shorts.
// Aliasing (read-once-after-flag): h1(t)->tile t+2; pre1(t)->tile t; h2(t)->pre0 slice t.
// MODE0 flags: FN[role][g] = 64 words; word [slot*8+w] set to t+1 by wave w of wg slot
// after draining its own stores. Consumers min-poll the 8-word line of the producer wg.
template<int MODE>
__device__ __forceinline__ void rnn_body(
    int role, int g, int slot, int tid, int w, int lane, int cl, int kh, int lrow,
    const unsigned short* pre0, unsigned short* bufP, unsigned short* h1buf,
    const float* bias1,
    unsigned int* FCA0, unsigned int* FCA1, unsigned int* FCB, unsigned int* FCC,
    unsigned int* FLA, unsigned int* FLB, unsigned int* FLC,
    unsigned int* FNA, unsigned int* FNB, unsigned int* FNC,
    const short8* wf, unsigned short* hl, unsigned short* outl)
{
  constexpr bool FAST = (MODE < 2);
  int n0 = slot*128 + w*16;
  int olocal = w*128 + ((cl>>3)*8 + kh*4)*8 + (cl&7);    // j stride 8 shorts
  int khc = kh & 1;
  unsigned int* myFL = ((role == 0) ? FLA : (role == 1) ? FLB : FLC) + slot;
  unsigned int* myFN = ((role == 0) ? FNA : (role == 1) ? FNB : FNC) + slot*8 + w;

  for (int t = 0; t < Tn; ++t){
    unsigned short* hlb = (MODE == 0) ? hl + (t & 1)*8192 : hl;
    const char* lbase = (const char*)hlb;

    float pv[4] = {0.f,0.f,0.f,0.f};
    if (role == 0 && kh < 2){            // prefetch pre0 (plain cached; slice immutable here)
      const unsigned short* pp = pre0 + ((size_t)t*Bn + g*8 + kh*4)*Hn + n0 + cl;
#pragma unroll
      for (int j=0;j<4;j++) pv[j] = bf2f(pp[(size_t)j*Hn]);
    }
    bool staged = true;
    if constexpr (MODE == 0){
      // ---- per-wave detect (min over producer wg's 8 wave-flags) + slice stage ----
      if (role == 0){
        if (t > 0){
          wait8_nt(FNA + w*8, (unsigned)t);
          stage_pw(h1buf + ((size_t)(t+1)*8 + g)*8192 + w*1024, hlb + w*1024, lane);
        } else staged = false;
      } else if (role == 1){
        wait8_nt(FNA + w*8, (unsigned)(t+1));
        stage_pw(h1buf + ((size_t)(t+2)*8 + g)*8192 + w*1024, hlb + w*1024, lane);
      } else {
        const unsigned short* pA = h1buf + ((size_t)t*8 + g)*8192 + slot*1024
                                   + ((w*16+cl)>>3)*64 + khc*32 + (cl&7);   // pre1(t), own cols
        if (t > 0){
          wait8_nt2(FNC + w*8, (unsigned)t, FNB + slot*8, (unsigned)(t+1));
          stage_pw_pv(bufP + ((size_t)(t-1)*Bn + g*8)*Hn + w*1024, hlb + w*1024, lane, pA, pv);
        } else {
          staged = false;
          wait8_nt(FNB + slot*8, 1u);
          ld4_chunk<true>(pA, pv);
        }
      }
    } else {
      // ---- fallback modes: centralized tid0 wait + B1 + full stage (r12/r9/r4-proven) ----
      if (tid == 0){
        if (role == 0)      wait_one <FAST>(FCA0, FLA, 8u*(unsigned)t, (unsigned)t);
        else if (role == 1) wait_one <FAST>(FCA1, FLA, 8u*(unsigned)(t+1), (unsigned)(t+1));
        else                wait_dual<FAST>(FCB, FLB, 8u*(unsigned)(t+1), (unsigned)(t+1),
                                            FCC, FLC, 8u*(unsigned)t, (unsigned)t);
      }
      __syncthreads();                                             // B1
      if (role == 0){
        if (t > 0) stage_lin<FAST>(h1buf + ((size_t)(t+1)*8 + g)*8192, hlb, tid);
        else staged = false;
      } else if (role == 1){
        stage_lin<FAST>(h1buf + ((size_t)(t+2)*8 + g)*8192, hlb, tid);
      } else {
        if (kh < 2)
          ld4_chunk<FAST>(h1buf + ((size_t)t*8 + g)*8192 + slot*1024 + ((w*16+cl)>>3)*64 + kh*32 + (cl&7), pv);
        if (t > 0) stage_lin<FAST>(bufP + ((size_t)(t-1)*Bn + g*8)*Hn, hlb, tid);
        else staged = false;
      }
    }
    __syncthreads();                                               // B2 (tile staged)
    // ---- compute ----
    f32x4 acc = {0.f,0.f,0.f,0.f};
    if (staged) acc = mfma_tile(lbase, wf, lrow, kh);
    // ---- transpose to wave-local LDS, vector-store tile slice ----
    if (kh < 2){
      float bs = (role == 1) ? bias1[n0 + cl] : 0.f;
#pragma unroll
      for (int j=0;j<4;j++){
        float v = acc[j] + pv[j] + bs;
        if (role != 1) v = tanh_fast(v);
        outl[olocal + j*8] = f2bf(v);
      }
    }
    // same-wave cross-lane via LDS (ds ordering within wave), then vector store
    unsigned short* tile;
    if (role == 0)      tile = h1buf + ((size_t)(t+2)*8 + g)*8192;
    else if (role == 1) tile = h1buf + ((size_t)t*8 + g)*8192;
    else                tile = bufP + ((size_t)t*Bn + g*8)*Hn;
    if (lane < 16){
      u32x4 v = *(const u32x4*)(outl + w*128 + lane*8);
      st16<FAST>(tile + slot*1024 + (w*16 + lane)*8, v);
    }
    if constexpr (MODE == 0){
      // per-wave publish: drain own stores, lane0 sets this wave's flag word. No barrier.
      asm volatile("s_waitcnt vmcnt(0)" ::: "memory");
      if (lane == 0)
        asm volatile("global_store_dword %0, %1, off sc0" :: "v"(myFN), "v"((unsigned)(t+1)) : "memory");
    } else {
      asm volatile("s_waitcnt vmcnt(0)" ::: "memory");
      __syncthreads();                                             // B3
      if (tid == 0){
        if constexpr (MODE == 1){
          if (role == 0){ atom_inc(FCA0); atom_inc(FCA1); }
          else if (role == 1) atom_inc(FCB);
          else atom_inc(FCC);
        } else {
          asm volatile("global_store_dword %0, %1, off sc0 sc1" :: "v"(myFL), "v"((unsigned)(t+1)) : "memory");
        }
      }
    }
  }
}

__launch_bounds__(512, 2)
__global__ void rnn_fused(const unsigned short* __restrict__ pre0_ro,
                          unsigned short* __restrict__ bufP,
                          unsigned short* __restrict__ h1buf,
                          const float* __restrict__ Whh0,
                          const float* __restrict__ Wih1,
                          const float* __restrict__ Whh1,
                          const float* __restrict__ bias1,
                          unsigned int* ctrs)
{
  __shared__ __align__(16) unsigned short hl[16384];   // 2 x 16KB staged tile (chunk order)
  __shared__ __align__(16) unsigned short outl[1024];  // 2KB, wave-private transpose
  __shared__ int s_mode;
  int bx = blockIdx.x;
  int g = bx & 7;
  int sub = bx >> 3;
  int role = sub >> 3, slot = sub & 7;
  int tid = threadIdx.x, lane = tid & 63, w = tid >> 6;
  int n0 = slot*128 + w*16;
  int cl = lane & 15, kh = lane >> 4, lrow = cl & 7;
  unsigned int* FLA = ctrs + (0*8 + g)*32;   // MALL flag lines (8 words each)
  unsigned int* FLB = ctrs + (1*8 + g)*32;
  unsigned int* FLC = ctrs + (2*8 + g)*32;
  unsigned int* arrive1 = ctrs + 768;
  unsigned int* badAT   = ctrs + 772;
  unsigned int* arrive2 = ctrs + 776;
  unsigned int* badNT   = ctrs + 780;
  unsigned int* arrive3 = ctrs + 784;
  unsigned int* FCA0 = ctrs + 1536 + (0*8 + g)*32;  // MODE1 counters (128B-spaced)
  unsigned int* FCB  = ctrs + 1536 + (1*8 + g)*32;
  unsigned int* FCC  = ctrs + 1536 + (2*8 + g)*32;
  unsigned int* FCA1 = ctrs + 1536 + (3*8 + g)*32;
  unsigned int* FNA = ctrs + 2560 + (0*8 + g)*64;   // MODE0 per-(slot,wave) flags, 64 words
  unsigned int* FNB = ctrs + 2560 + (1*8 + g)*64;
  unsigned int* FNC = ctrs + 2560 + (2*8 + g)*64;

  // ---- one-time self-tests: NT sequence, then ATOM sequence; consensus via bad flags ----
  if (tid == 0){
    int xcc;
    asm volatile("s_getreg_b32 %0, hwreg(HW_REG_XCC_ID)" : "=s"(xcc));
    unsigned int* atw = ctrs + 1024 + g*32;  unsigned int* atarmed = atw + 16;
    unsigned int* ntw = ctrs + 1280 + g*32;  unsigned int* ntarmed = ntw + 16;
    if (xcc != g){
      __hip_atomic_fetch_or(badNT, 1u, __ATOMIC_RELAXED, __HIP_MEMORY_SCOPE_AGENT);
      __hip_atomic_fetch_or(badAT, 1u, __ATOMIC_RELAXED, __HIP_MEMORY_SCOPE_AGENT);
    }
    unsigned pr = ld1_nt(ntw) + ld1_nt(ntarmed);   // prime NT lines (stale-L1 hazard probe)
    asm volatile("" :: "v"(pr));
    __hip_atomic_fetch_add(arrive1, 1u, __ATOMIC_ACQ_REL, __HIP_MEMORY_SCOPE_AGENT);
    int t1 = 0;
    for (int i = 0; i < (1 << 20); ++i){
      if (__hip_atomic_load(arrive1, __ATOMIC_ACQUIRE, __HIP_MEMORY_SCOPE_AGENT) >= 192u){ t1 = 1; break; }
      __builtin_amdgcn_s_sleep(2);
    }
    if (!t1){
      __hip_atomic_fetch_or(badNT, 1u, __ATOMIC_RELAXED, __HIP_MEMORY_SCOPE_AGENT);
      __hip_atomic_fetch_or(badAT, 1u, __ATOMIC_RELAXED, __HIP_MEMORY_SCOPE_AGENT);
    }
    unsigned magicN = 0xBEEF0000u | (unsigned)g;
    if (sub == 0){
      asm volatile("global_store_dword %0, %1, off sc0\n\t"
                   "s_waitcnt vmcnt(0)\n\t"
                   "global_store_dword %2, %3, off sc0"
                   :: "v"(ntw), "v"(magicN), "v"(ntarmed), "v"(1u) : "memory");
    }
    int okN = 0;
    for (int i = 0; i < (1 << 14); ++i){
      if (ld1_nt(ntarmed) == 1u){ okN = (ld1_nt(ntw) == magicN); break; }
      if (i > 8) __builtin_amdgcn_s_sleep(1);
    }
    if (!okN) __hip_atomic_fetch_or(badNT, 1u, __ATOMIC_RELAXED, __HIP_MEMORY_SCOPE_AGENT);
    __hip_atomic_fetch_add(arrive2, 1u, __ATOMIC_ACQ_REL, __HIP_MEMORY_SCOPE_AGENT);
    int t2 = 0;
    for (int i = 0; i < (1 << 20); ++i){
      if (__hip_atomic_load(arrive2, __ATOMIC_ACQUIRE, __HIP_MEMORY_SCOPE_AGENT) >= 192u){ t2 = 1; break; }
      __builtin_amdgcn_s_sleep(2);
    }
    if (!t2){
      __hip_atomic_fetch_or(badNT, 1u, __ATOMIC_RELAXED, __HIP_MEMORY_SCOPE_AGENT);
      __hip_atomic_fetch_or(badAT, 1u, __ATOMIC_RELAXED, __HIP_MEMORY_SCOPE_AGENT);
    }
    unsigned magicA = 0xCAFE0000u | (unsigned)g;
    if (sub == 0){
      asm volatile("global_store_dword %0, %1, off sc0\n\t"
                   "s_waitcnt vmcnt(0)" :: "v"(atw), "v"(magicA) : "memory");
      atom_inc(atarmed);
    }
    int okA = 0;
    for (int i = 0; i < (1 << 15); ++i){
      if (atom_poll(atarmed) >= 1u){ okA = (ld1_sc0(atw) == magicA); break; }
      if (i > 16) __builtin_amdgcn_s_sleep(1);
    }
    if (!okA) __hip_atomic_fetch_or(badAT, 1u, __ATOMIC_RELAXED, __HIP_MEMORY_SCOPE_AGENT);
    __hip_atomic_fetch_add(arrive3, 1u, __ATOMIC_ACQ_REL, __HIP_MEMORY_SCOPE_AGENT);
    int t3 = 0;
    for (int i = 0; i < (1 << 20); ++i){
      if (__hip_atomic_load(arrive3, __ATOMIC_ACQUIRE, __HIP_MEMORY_SCOPE_AGENT) >= 192u){ t3 = 1; break; }
      __builtin_amdgcn_s_sleep(2);
    }
    unsigned bN = __hip_atomic_load(badNT, __ATOMIC_ACQUIRE, __HIP_MEMORY_SCOPE_AGENT);
    unsigned bA = __hip_atomic_load(badAT, __ATOMIC_ACQUIRE, __HIP_MEMORY_SCOPE_AGENT);
    s_mode = (!t3) ? 2 : (bN == 0u ? 0 : (bA == 0u ? 1 : 2));
  }
  __syncthreads();
  const int mode = s_mode;

  // Resident weight slice as MFMA B-fragments: lane holds W[n0+cl][kk*32+kh*8+0..7]
  const float* Wmat = (role == 0) ? Whh0 : (role == 1) ? Wih1 : Whh1;
  short8 wf[32];
  {
    const float* wr = Wmat + (size_t)(n0 + cl)*Hn + kh*8;
#pragma unroll
    for (int kk = 0; kk < 32; ++kk){
      float4 a = *(const float4*)(wr + kk*32);
      float4 b = *(const float4*)(wr + kk*32 + 4);
      short8 v;
      v[0]=(short)f2bf(a.x); v[1]=(short)f2bf(a.y); v[2]=(short)f2bf(a.z); v[3]=(short)f2bf(a.w);
      v[4]=(short)f2bf(b.x); v[5]=(short)f2bf(b.y); v[6]=(short)f2bf(b.z); v[7]=(short)f2bf(b.w);
      wf[kk] = v;
    }
  }

  if (mode == 0)
    rnn_body<0>(role, g, slot, tid, w, lane, cl, kh, lrow, pre0_ro, bufP, h1buf,
                bias1, FCA0, FCA1, FCB, FCC, FLA, FLB, FLC, FNA, FNB, FNC, wf, hl, outl);
  else if (mode == 1)
    rnn_body<1>(role, g, slot, tid, w, lane, cl, kh, lrow, pre0_ro, bufP, h1buf,
                bias1, FCA0, FCA1, FCB, FCC, FLA, FLB, FLC, FNA, FNB, FNC, wf, hl, outl);
  else
    rnn_body<2>(role, g, slot, tid, w, lane, cl, kh, lrow, pre0_ro, bufP, h1buf,
                bias1, FCA0, FCA1, FCB, FCC, FLA, FLB, FLC, FNA, FNB, FNC, wf, hl, outl);
}

// ---------------- FC head: out[b][o] = h2[b][T-1][:] . Wfc[o][:] + bfc[o] ----------------
__global__ void fc_k(const unsigned short* __restrict__ bufP,
                     const float* __restrict__ Wfc, const float* __restrict__ bfc,
                     float* __restrict__ out)
{
  int gw = (blockIdx.x * blockDim.x + threadIdx.x) >> 6;
  int lane = threadIdx.x & 63;
  int b = gw >> 7, o = gw & 127;
  // h2(T-1) lives in pre0 slice T-1, group tile (b>>3), chunk-ordered
  const unsigned short* tile = bufP + ((size_t)(Tn-1)*Bn + (b & ~7))*Hn;
  int r = b & 7;
  const float* wr = Wfc + (size_t)o*Hn;
  float s = 0.f;
  for (int k = lane; k < Hn; k += 64)
    s += bf2f(tile[((k>>3)*8 + r)*8 + (k&7)]) * wr[k];
#pragma unroll
  for (int off = 32; off > 0; off >>= 1) s += __shfl_down(s, off, 64);
  if (lane == 0) out[b*OUTn + o] = s + bfc[o];
}

// ---------------- host ----------------
extern "C" void kernel_launch(void* const* d_in, const int* in_sizes, int n_in,
                              void* d_out, int out_size, void* d_ws, size_t ws_size,
                              hipStream_t stream)
{
  const float* x    = (const float*)d_in[0];
  const float* Wih0 = (const float*)d_in[1];
  const float* Whh0 = (const float*)d_in[2];
  const float* bih0 = (const float*)d_in[3];
  const float* bhh0 = (const float*)d_in[4];
  const float* Wih1 = (const float*)d_in[5];
  const float* Whh1 = (const float*)d_in[6];
  const float* bih1 = (const float*)d_in[7];
  const float* bhh1 = (const float*)d_in[8];
  const float* Wfc  = (const float*)d_in[9];
  const float* bfc  = (const float*)d_in[10];
  float* out = (float*)d_out;

  // workspace (bf16 elements)
  unsigned short* bufP  = (unsigned short*)d_ws;                    // pre0 [T][B][H]; h2 aliases slices
  unsigned short* h1buf = bufP  + (size_t)Bn*Tn*Hn;                 // (T+2)*8 chunk-ordered 16KB tiles
  unsigned short* wih0b = h1buf + (size_t)(Tn+2)*8*8192;            // 1MiB
  float* bias0 = (float*)(wih0b + (size_t)Hn*DINn);
  float* bias1 = bias0 + Hn;
  unsigned int* ctrs = (unsigned int*)(bias1 + Hn);                 // 4096 uints

  hipMemsetAsync(ctrs, 0, 4096*sizeof(unsigned int), stream);

  cvt_bf16x8<<<256, 256, 0, stream>>>(Wih0, wih0b, (long long)Hn*DINn/8);
  bias_combine<<<4, 256, 0, stream>>>(bih0, bhh0, bias0, bih1, bhh1, bias1);

  // pre0 = x @ Wih0^T + bias0, written as [T][B][H]
  dim3 g1(Hn/128, (Bn*Tn)/128);
  gemm_pre0<<<g1, 256, 0, stream>>>(x, wih0b, bias0, bufP, Hn, DINn);

  // fused 3-stage pipeline (MODE0: per-wave detect + per-wave publish; ATOM/MALL fallback)
  rnn_fused<<<192, 512, 0, stream>>>(bufP, bufP, h1buf, Whh0, Wih1, Whh1, bias1, ctrs);

  // FC head from h2(T-1) (aliased into pre0 slice T-1)
  fc_k<<<2048, 256, 0, stream>>>(bufP, Wfc, bfc, out);
}